// Round 2
// baseline (3869.619 us; speedup 1.0000x reference)
//
#include <hip/hip_runtime.h>

#define NB 1024
#define NV 96
#define WW 128
#define EE 64
#define DD 64

typedef _Float16 h2t __attribute__((ext_vector_type(2)));
typedef float f2t __attribute__((ext_vector_type(2)));
typedef float f4t __attribute__((ext_vector_type(4)));

#define CLOG 2.885390081777927f   /* 2*log2(e) */
#define L2E  1.4426950408889634f  /* log2(e)   */

__device__ __forceinline__ float fdot2(h2t a, h2t b, float c) {
    return __builtin_amdgcn_fdot2(a, b, c, false);
}
__device__ __forceinline__ h2t pk2(float a, float b) {
    h2t r; r.x = (_Float16)a; r.y = (_Float16)b; return r;
}
__device__ __forceinline__ h2t bch(float f) { return __builtin_bit_cast(h2t, f); }
__device__ __forceinline__ float ex2(float x) { return __builtin_amdgcn_exp2f(x); }
__device__ __forceinline__ float rcp_(float x) { return __builtin_amdgcn_rcpf(x); }
__device__ __forceinline__ float sig_c(float x) { return rcp_(1.f + ex2(-x * L2E)); }
__device__ __forceinline__ float tanh_c(float x) { return 1.f - 2.f * rcp_(ex2(x * CLOG) + 1.f); }
__device__ __forceinline__ float wsum(float v) {
#pragma unroll
    for (int o = 32; o; o >>= 1) v += __shfl_xor(v, o, 64);
    return v;
}

// 4 fdot2 from one f4 of packed-half pairs
#define DOT4(V, WR, B, ACC) do { \
    ACC = fdot2(bch((V).x), (WR)[(B) + 0], ACC); \
    ACC = fdot2(bch((V).y), (WR)[(B) + 1], ACC); \
    ACC = fdot2(bch((V).z), (WR)[(B) + 2], ACC); \
    ACC = fdot2(bch((V).w), (WR)[(B) + 3], ACC); } while (0)

template<bool HSG>
__global__ __launch_bounds__(256, 4) void darnn_kernel(
    const float* __restrict__ x,
    const float* __restrict__ eWih, const float* __restrict__ eWhh,
    const float* __restrict__ ebih, const float* __restrict__ ebhh,
    const float* __restrict__ elv,  const float* __restrict__ elw,
    const float* __restrict__ elwb, const float* __restrict__ elu,
    const float* __restrict__ elub,
    const float* __restrict__ dWih, const float* __restrict__ dWhh,
    const float* __restrict__ dbih, const float* __restrict__ dbhh,
    const float* __restrict__ dlv,  const float* __restrict__ dlw,
    const float* __restrict__ dlwb, const float* __restrict__ dlu,
    const float* __restrict__ dlub, const float* __restrict__ dlp,
    const float* __restrict__ dlpb, const float* __restrict__ dly,
    const float* __restrict__ dlyb, const int* __restrict__ tgtp,
    h2t* __restrict__ hsg_all,
    float* __restrict__ out)
{
    // u_e: h2t[96][64] XOR-swizzled (scaled by CLOG) | later u_d: h2t[128][32] swizzled
    __shared__ __align__(16) h2t  s_pool[96 * 64];
    __shared__ __align__(16) h2t  s_hseq2[HSG ? 1 : WW][32];  // fallback h_seq (swizzled)
    __shared__ __align__(16) f4t  s_wlv[64];    // {wo0*C, wo1*C, lv0, lv1}
    __shared__ __align__(16) float s_tmp[256];
    __shared__ __align__(16) float s_soft[128];
    __shared__ __align__(16) h2t  s_hch2[2][64]; // double-buffered packed [h,c] pairs
    __shared__ __align__(16) h2t  s_xt[48];

    float* s_wlvf = (float*)s_wlv;

    const int tid  = threadIdx.x;
    const int b    = blockIdx.x;
    const int lane = tid & 63, wq = tid >> 6;
    const int uidx = wq * 16 + (lane >> 2);      // unit owned (redundant x4)
    const int jrow = (lane & 3) * 64 + uidx;     // gate row owned
    const float* xb = x + (size_t)b * NV * WW;
    h2t* hsgb = HSG ? (hsg_all + (size_t)b * (WW * 32)) : (h2t*)nullptr;

    float c_reg = 0.f;

    // ---------------- init ----------------
    if (tid >= 96 && tid < 128) s_soft[tid] = 0.f;
    if (tid < 64) {
        s_hch2[0][tid] = pk2(0.f, 0.f);
        s_wlvf[tid * 4 + 2] = elv[2 * tid];
        s_wlvf[tid * 4 + 3] = elv[2 * tid + 1];
    }

    // ---------------- phase A: u_e (scaled, fp16, swizzled), barrier-free ----
    {
        const int o = tid >> 1, p = tid & 1;
        f4t lu4[16];
        const f4t* lur = (const f4t*)(elu + o * WW + p * 64);
#pragma unroll
        for (int i = 0; i < 16; ++i) lu4[i] = lur[i];
        const float lub_o = elub[o];
        for (int n = 0; n < NV; ++n) {
            const f4t* xr = (const f4t*)(xb + n * WW + p * 64);
            float a = 0.f;
#pragma unroll
            for (int i = 0; i < 16; ++i) {
                f4t v = xr[i], l4 = lu4[i];
                a = fmaf(v.x, l4.x, a); a = fmaf(v.y, l4.y, a);
                a = fmaf(v.z, l4.z, a); a = fmaf(v.w, l4.w, a);
            }
            a += __shfl_xor(a, 1, 64);
            float val = (a + lub_o) * CLOG;
            float vn  = __shfl_xor(val, 2, 64);
            if (!(tid & 3)) s_pool[n * 64 + ((tid >> 2) ^ (n & 31))] = pk2(val, vn);
        }
    }
    __syncthreads();

    float elvsum;
    {
        const f2t lvp = *(const f2t*)&s_wlvf[(tid & 63) * 4 + 2];
        elvsum = wsum(lvp.x + lvp.y);
    }

    // ---------------- encoder weights -> fp16-pair registers ----
    h2t lw_r[32];
    {
        const f2t* r = (const f2t*)(elw + (tid >> 1) * 128 + (tid & 1) * 64);
#pragma unroll
        for (int i = 0; i < 32; ++i) { f2t v = r[i]; lw_r[i] = pk2(v.x, v.y); }
    }
    const float lwb_r = elwb[tid >> 1];
    h2t wih_r[48];
    {
        const f2t* r = (const f2t*)(eWih + jrow * 96);
#pragma unroll
        for (int i = 0; i < 48; ++i) { f2t v = r[i]; wih_r[i] = pk2(v.x, v.y); }
    }
    h2t whh_r[32];
    {
        const f2t* r = (const f2t*)(eWhh + jrow * 64);
#pragma unroll
        for (int i = 0; i < 32; ++i) { f2t v = r[i]; whh_r[i] = pk2(v.x, v.y); }
    }
    const float bsum_r = ebih[jrow] + ebhh[jrow];

    // ---------------- encoder recurrence: 4 barriers/step ----
#pragma unroll 1
    for (int t = 0; t < WW; ++t) {
        const int pp = t & 1;
        // ph1: w_out via pair-split + shfl combine; prefetch x column
        float xv = 0.f;
        if (!(tid & 1) && tid < 192) xv = xb[(tid >> 1) * WW + t];
        {
            const f4t* hc4 = (const f4t*)&s_hch2[pp][(tid & 1) * 32];
            float a = 0.f;
#pragma unroll
            for (int i = 0; i < 8; ++i) { f4t v = hc4[i]; DOT4(v, lw_r, 4 * i, a); }
            a += __shfl_xor(a, 1, 64);
            float wo = (a + lwb_r) * CLOG;
            float wn = __shfl_xor(wo, 2, 64);
            if (!(tid & 3)) { f2t st = {wo, wn}; *(f2t*)&s_wlvf[(tid >> 2) * 4] = st; }
        }
        __syncthreads();
        // ph2: scores (tanh trick) + exp, shfl-combined
        float prod = 0.f;
        if (tid < 192) {
            const int n = tid >> 1, sw = n & 31;
            const h2t* uer = s_pool + n * 64;
            float a = 0.f;
#pragma unroll
            for (int j = 0; j < 32; ++j) {
                const int wp = (tid & 1) * 32 + j;
                f4t wl = s_wlv[wp];
                h2t u  = uer[wp ^ sw];
                float r0 = rcp_(ex2(wl.x + (float)u.x) + 1.f);
                float r1 = rcp_(ex2(wl.y + (float)u.y) + 1.f);
                a = fmaf(wl.z, r0, a);
                a = fmaf(wl.w, r1, a);
            }
            a += __shfl_xor(a, 1, 64);
            if (!(tid & 1)) {
                float e = ex2((elvsum - 2.f * a) * L2E);
                prod = e * xv;
                s_soft[n] = e;
            }
        }
        __syncthreads();
        // ph3: normalize + x_tilde
        if (tid < 192) {
            const int l = tid & 63;
            float sm = s_soft[l] + s_soft[64 + l];   // [96..127] are zeros
            sm = wsum(sm);
            float inv = rcp_(sm);
            float p1 = __shfl_xor(prod, 2, 64);
            if (!(tid & 3)) s_xt[tid >> 2] = pk2(prod * inv, p1 * inv);
        }
        __syncthreads();
        // ph4: gates + fused LSTM update (quad-gate layout)
        {
            float gv = bsum_r;
            const f4t* xt4 = (const f4t*)s_xt;
#pragma unroll
            for (int i = 0; i < 12; ++i) { f4t v = xt4[i]; DOT4(v, wih_r, 4 * i, gv); }
            const f4t* h4 = (const f4t*)&s_hch2[pp][0];
#pragma unroll
            for (int i = 0; i < 8; ++i) { f4t v = h4[i]; DOT4(v, whh_r, 4 * i, gv); }
            const int base = lane & ~3;
            float gi = __shfl(gv, base, 64);
            float gf = __shfl(gv, base + 1, 64);
            float g2 = __shfl(gv, base + 2, 64);
            float go = __shfl(gv, base + 3, 64);
            float c = sig_c(gf) * c_reg + sig_c(gi) * tanh_c(g2);
            float h = sig_c(go) * tanh_c(c);
            c_reg = c;
            float hn = __shfl_xor(h, 4, 64);
            float cn = __shfl_xor(c, 4, 64);
            if (!(lane & 7)) {
                const int k = wq * 8 + (lane >> 3);
                s_hch2[pp ^ 1][k]      = pk2(h, hn);
                s_hch2[pp ^ 1][32 + k] = pk2(c, cn);
                if constexpr (HSG) hsgb[t * 32 + k] = pk2(h, hn);
                else               s_hseq2[t][k ^ (t & 31)] = pk2(h, hn);
            }
        }
        __syncthreads();
    }

    // ---------------- u_d = h_seq @ dlu^T + dlub (scaled fp16, swizzled into pool) ----
    {
        const int e2h = tid & 31;
        h2t du0[32], du1[32];
        {
            const f4t* p0 = (const f4t*)(dlu + (2 * e2h) * 64);
            const f4t* p1 = (const f4t*)(dlu + (2 * e2h + 1) * 64);
#pragma unroll
            for (int i = 0; i < 16; ++i) {
                f4t v0 = p0[i], v1 = p1[i];
                du0[2 * i] = pk2(v0.x, v0.y); du0[2 * i + 1] = pk2(v0.z, v0.w);
                du1[2 * i] = pk2(v1.x, v1.y); du1[2 * i + 1] = pk2(v1.z, v1.w);
            }
        }
        const float b0 = dlub[2 * e2h], b1 = dlub[2 * e2h + 1];
#pragma unroll 1
        for (int pass = 0; pass < 16; ++pass) {
            const int w = pass * 8 + (tid >> 5);
            float a0 = b0, a1 = b1;
            if constexpr (HSG) {
                const f4t* hr = (const f4t*)(hsgb + w * 32);
#pragma unroll
                for (int i = 0; i < 8; ++i) {
                    f4t v = hr[i];
                    DOT4(v, du0, 4 * i, a0);
                    DOT4(v, du1, 4 * i, a1);
                }
            } else {
                const int sww = w & 31;
#pragma unroll
                for (int i = 0; i < 32; ++i) {
                    h2t hp = s_hseq2[w][i ^ sww];
                    a0 = fdot2(hp, du0[i], a0);
                    a1 = fdot2(hp, du1[i], a1);
                }
            }
            s_pool[w * 32 + (e2h ^ (w & 31))] = pk2(a0 * CLOG, a1 * CLOG);
        }
    }

    // ---------------- decoder setup ----------------
    const int tgt = tgtp[0];
    if (tid < 32) {
        s_wlvf[tid * 4 + 2] = dlv[2 * tid];
        s_wlvf[tid * 4 + 3] = dlv[2 * tid + 1];
    }
    if (tid < 64) s_hch2[0][tid] = pk2(0.f, 0.f);
    float dlvsum;
    { float v = dlv[tid & 63]; dlvsum = wsum(v); }
    h2t dlw_r[16];
    {
        const f2t* r = (const f2t*)(dlw + (tid >> 2) * 128 + (tid & 3) * 32);
#pragma unroll
        for (int i = 0; i < 16; ++i) { f2t v = r[i]; dlw_r[i] = pk2(v.x, v.y); }
    }
    const float dlwb_r = dlwb[tid >> 2];
    h2t dwhh_r[32];
    {
        const f2t* r = (const f2t*)(dWhh + jrow * 64);
#pragma unroll
        for (int i = 0; i < 32; ++i) { f2t v = r[i]; dwhh_r[i] = pk2(v.x, v.y); }
    }
    const float dwih_r  = dWih[jrow];
    const float dbsum_r = dbih[jrow] + dbhh[jrow];
    const float lp0     = dlp[0];
    const float lp1_r   = dlp[1 + (tid & 63)];
    const float lpb     = dlpb[0];
    c_reg = 0.f;
    float h_reg = 0.f;
    __syncthreads();

    // ---------------- decoder recurrence: 4 barriers/step ----
#pragma unroll 1
    for (int s = 0; s < WW - 1; ++s) {
        const int pp = s & 1;
        const float ys = xb[(size_t)tgt * WW + s];
        // ph1: w_out_d via quad-split + shfl
        {
            const f4t* hc4 = (const f4t*)&s_hch2[pp][(tid & 3) * 16];
            float a = 0.f;
#pragma unroll
            for (int i = 0; i < 4; ++i) { f4t v = hc4[i]; DOT4(v, dlw_r, 4 * i, a); }
            a += __shfl_xor(a, 1, 64);
            a += __shfl_xor(a, 2, 64);
            float wo = (a + dlwb_r) * CLOG;
            float wn = __shfl_xor(wo, 4, 64);
            if (!(tid & 7)) { f2t st = {wo, wn}; *(f2t*)&s_wlvf[(tid >> 3) * 4] = st; }
        }
        __syncthreads();
        // ph2: v scores + exp
        {
            const int w = tid >> 1, sw = w & 31;
            const h2t* udr = s_pool + w * 32;
            float a = 0.f;
#pragma unroll
            for (int j = 0; j < 16; ++j) {
                const int ep = (tid & 1) * 16 + j;
                f4t wl = s_wlv[ep];
                h2t u  = udr[ep ^ sw];
                float r0 = rcp_(ex2(wl.x + (float)u.x) + 1.f);
                float r1 = rcp_(ex2(wl.y + (float)u.y) + 1.f);
                a = fmaf(wl.z, r0, a);
                a = fmaf(wl.w, r1, a);
            }
            a += __shfl_xor(a, 1, 64);
            if (!(tid & 1)) s_soft[w] = ex2((dlvsum - 2.f * a) * L2E);
        }
        __syncthreads();
        // ph3: inv + context partials
        float inv;
        {
            const int l = tid & 63;
            float sm = s_soft[l] + s_soft[64 + l];
            sm = wsum(sm);
            inv = rcp_(sm);
            const int e2 = tid & 31, pg = tid >> 5;
            float a0 = 0.f, a1 = 0.f;
#pragma unroll
            for (int j = 0; j < 16; ++j) {
                const int w = pg * 16 + j;
                float bw = s_soft[w];
                h2t hp;
                if constexpr (HSG) hp = hsgb[w * 32 + e2];
                else               hp = s_hseq2[w][e2 ^ (w & 31)];
                a0 = fmaf(bw, (float)hp.x, a0);
                a1 = fmaf(bw, (float)hp.y, a1);
            }
            a0 += __shfl_xor(a0, 32, 64);
            a1 += __shfl_xor(a1, 32, 64);
            if ((tid & 63) < 32) { f2t st = {a0, a1}; *(f2t*)&s_tmp[wq * 64 + e2 * 2] = st; }
        }
        __syncthreads();
        // ph4: y_tilde (redundant) + gates + fused update
        {
            const int l = tid & 63;
            float ctx = s_tmp[l] + s_tmp[64 + l] + s_tmp[128 + l] + s_tmp[192 + l];
            float term = ctx * inv * lp1_r;
            term = wsum(term);
            float yt = fmaf(ys, lp0, term + lpb);
            float gv = fmaf(yt, dwih_r, dbsum_r);
            const f4t* h4 = (const f4t*)&s_hch2[pp][0];
#pragma unroll
            for (int i = 0; i < 8; ++i) { f4t v = h4[i]; DOT4(v, dwhh_r, 4 * i, gv); }
            const int base = l & ~3;
            float gi = __shfl(gv, base, 64);
            float gf = __shfl(gv, base + 1, 64);
            float g2 = __shfl(gv, base + 2, 64);
            float go = __shfl(gv, base + 3, 64);
            float c = sig_c(gf) * c_reg + sig_c(gi) * tanh_c(g2);
            float h = sig_c(go) * tanh_c(c);
            c_reg = c; h_reg = h;
            float hn = __shfl_xor(h, 4, 64);
            float cn = __shfl_xor(c, 4, 64);
            if (!(l & 7)) {
                const int k = wq * 8 + (l >> 3);
                s_hch2[pp ^ 1][k]      = pk2(h, hn);
                s_hch2[pp ^ 1][32 + k] = pk2(c, cn);
            }
        }
        __syncthreads();
    }

    // ---------------- output: out[b] = [h,c] . dly + dlyb ----------------
    {
        float term = 0.f;
        if (!(lane & 3)) term = h_reg * dly[uidx] + c_reg * dly[64 + uidx];
        term = wsum(term);
        if (lane == 0) s_tmp[wq] = term;
    }
    __syncthreads();
    if (tid == 0) out[b] = s_tmp[0] + s_tmp[1] + s_tmp[2] + s_tmp[3] + dlyb[0];
}

extern "C" void kernel_launch(void* const* d_in, const int* in_sizes, int n_in,
                              void* d_out, int out_size, void* d_ws, size_t ws_size,
                              hipStream_t stream) {
    (void)in_sizes; (void)n_in; (void)out_size;
    const float* x    = (const float*)d_in[0];
    const float* eWih = (const float*)d_in[1];
    const float* eWhh = (const float*)d_in[2];
    const float* ebih = (const float*)d_in[3];
    const float* ebhh = (const float*)d_in[4];
    const float* elv  = (const float*)d_in[5];
    const float* elw  = (const float*)d_in[6];
    const float* elwb = (const float*)d_in[7];
    const float* elu  = (const float*)d_in[8];
    const float* elub = (const float*)d_in[9];
    const float* dWih = (const float*)d_in[10];
    const float* dWhh = (const float*)d_in[11];
    const float* dbih = (const float*)d_in[12];
    const float* dbhh = (const float*)d_in[13];
    const float* dlv  = (const float*)d_in[14];
    const float* dlw  = (const float*)d_in[15];
    const float* dlwb = (const float*)d_in[16];
    const float* dlu  = (const float*)d_in[17];
    const float* dlub = (const float*)d_in[18];
    const float* dlp  = (const float*)d_in[19];
    const float* dlpb = (const float*)d_in[20];
    const float* dly  = (const float*)d_in[21];
    const float* dlyb = (const float*)d_in[22];
    const int*   tgt  = (const int*)d_in[23];
    float* out = (float*)d_out;

    const size_t need = (size_t)NB * WW * 32 * sizeof(h2t);  // 16 MiB
    if (d_ws && ws_size >= need) {
        darnn_kernel<true><<<NB, 256, 0, stream>>>(
            x, eWih, eWhh, ebih, ebhh, elv, elw, elwb, elu, elub,
            dWih, dWhh, dbih, dbhh, dlv, dlw, dlwb, dlu, dlub,
            dlp, dlpb, dly, dlyb, tgt, (h2t*)d_ws, out);
    } else {
        darnn_kernel<false><<<NB, 256, 0, stream>>>(
            x, eWih, eWhh, ebih, ebhh, elv, elw, elwb, elu, elub,
            dWih, dWhh, dbih, dbhh, dlv, dlw, dlwb, dlu, dlub,
            dlp, dlpb, dly, dlyb, tgt, (h2t*)nullptr, out);
    }
}

// Round 3
// 3805.433 us; speedup vs baseline: 1.0169x; 1.0169x over previous
//
#include <hip/hip_runtime.h>

#define NB 1024
#define NV 96
#define WW 128
#define EE 64
#define DD 64

typedef _Float16 h2t __attribute__((ext_vector_type(2)));
typedef float f2t __attribute__((ext_vector_type(2)));
typedef float f4t __attribute__((ext_vector_type(4)));

#define CLOG 2.885390081777927f   /* 2*log2(e) */
#define L2E  1.4426950408889634f  /* log2(e)   */

__device__ __forceinline__ float fdot2(h2t a, h2t b, float c) {
    return __builtin_amdgcn_fdot2(a, b, c, false);
}
__device__ __forceinline__ h2t pk2(float a, float b) {
    h2t r; r.x = (_Float16)a; r.y = (_Float16)b; return r;
}
__device__ __forceinline__ h2t bch(float f) { return __builtin_bit_cast(h2t, f); }
__device__ __forceinline__ float bcf(h2t p) { return __builtin_bit_cast(float, p); }
__device__ __forceinline__ float ex2(float x) { return __builtin_amdgcn_exp2f(x); }
__device__ __forceinline__ float rcp_(float x) { return __builtin_amdgcn_rcpf(x); }
__device__ __forceinline__ float sig_c(float x) { return rcp_(1.f + ex2(-x * L2E)); }
__device__ __forceinline__ float tanh_c(float x) { return 1.f - 2.f * rcp_(ex2(x * CLOG) + 1.f); }
__device__ __forceinline__ float wsum(float v) {
#pragma unroll
    for (int o = 32; o; o >>= 1) v += __shfl_xor(v, o, 64);
    return v;
}

// 4 fdot2 from one f4 of packed-half pairs
#define DOT4(V, WR, B, ACC) do { \
    ACC = fdot2(bch((V).x), (WR)[(B) + 0], ACC); \
    ACC = fdot2(bch((V).y), (WR)[(B) + 1], ACC); \
    ACC = fdot2(bch((V).z), (WR)[(B) + 2], ACC); \
    ACC = fdot2(bch((V).w), (WR)[(B) + 3], ACC); } while (0)

// dot a f4 of activation-pairs with a f4 of LDS-held weight-pairs
#define DOT4W(V, W4, ACC) do { \
    ACC = fdot2(bch((V).x), bch((W4).x), ACC); \
    ACC = fdot2(bch((V).y), bch((W4).y), ACC); \
    ACC = fdot2(bch((V).z), bch((W4).z), ACC); \
    ACC = fdot2(bch((V).w), bch((W4).w), ACC); } while (0)

template<bool HSG>
__global__ __launch_bounds__(256) __attribute__((amdgpu_waves_per_eu(4, 4)))
void darnn_kernel(
    const float* __restrict__ x,
    const float* __restrict__ eWih, const float* __restrict__ eWhh,
    const float* __restrict__ ebih, const float* __restrict__ ebhh,
    const float* __restrict__ elv,  const float* __restrict__ elw,
    const float* __restrict__ elwb, const float* __restrict__ elu,
    const float* __restrict__ elub,
    const float* __restrict__ dWih, const float* __restrict__ dWhh,
    const float* __restrict__ dbih, const float* __restrict__ dbhh,
    const float* __restrict__ dlv,  const float* __restrict__ dlw,
    const float* __restrict__ dlwb, const float* __restrict__ dlu,
    const float* __restrict__ dlub, const float* __restrict__ dlp,
    const float* __restrict__ dlpb, const float* __restrict__ dly,
    const float* __restrict__ dlyb, const int* __restrict__ tgtp,
    h2t* __restrict__ hsg_all,
    float* __restrict__ out)
{
    // u_e: h2t[96][64] XOR-swizzled (scaled by CLOG) | later u_d: h2t[128][32] swizzled
    __shared__ __align__(16) h2t  s_pool[96 * 64];                 // 24576 B
    __shared__ __align__(16) h2t  s_hseq2[HSG ? 1 : WW][32];       // fallback h_seq
    __shared__ __align__(16) f4t  s_wlv[64];                       // 1024 B {wo0*C, wo1*C, lv0, lv1}
    __shared__ __align__(16) char s_u2[1024];                      // enc: s_xt h2t[48] | dec: s_tmp f[256]
    __shared__ __align__(16) float s_soft[128];                    // 512 B
    __shared__ __align__(16) h2t  s_hch2[2][64];                   // 512 B double-buffered [h,c] pairs
    __shared__ __align__(16) f4t  s_spillh[2][256];                // 8192 B  eWhh pairs 24..31 (per tid)
    __shared__ __align__(16) f4t  s_spillw[256];                   // 4096 B  eWih pairs 44..47 (per tid)

    float* s_wlvf = (float*)s_wlv;
    h2t*  const s_xt  = (h2t*)s_u2;
    float* const s_tmp = (float*)s_u2;

    const int tid  = threadIdx.x;
    const int b    = blockIdx.x;
    const int lane = tid & 63, wq = tid >> 6;
    const int uidx = wq * 16 + (lane >> 2);      // unit owned (redundant x4)
    const int jrow = (lane & 3) * 64 + uidx;     // gate row owned
    const float* xb = x + (size_t)b * NV * WW;
    h2t* hsgb = HSG ? (hsg_all + (size_t)b * (WW * 32)) : (h2t*)nullptr;

    float c_reg = 0.f;

    // ---------------- init ----------------
    if (tid >= 96 && tid < 128) s_soft[tid] = 0.f;
    if (tid < 64) {
        s_hch2[0][tid] = pk2(0.f, 0.f);
        s_wlvf[tid * 4 + 2] = elv[2 * tid];
        s_wlvf[tid * 4 + 3] = elv[2 * tid + 1];
    }

    // ---------------- phase A: u_e (scaled, fp16, swizzled), barrier-free ----
    {
        const int o = tid >> 1, p = tid & 1;
        f4t lu4[16];
        const f4t* lur = (const f4t*)(elu + o * WW + p * 64);
#pragma unroll
        for (int i = 0; i < 16; ++i) lu4[i] = lur[i];
        const float lub_o = elub[o];
        for (int n = 0; n < NV; ++n) {
            const f4t* xr = (const f4t*)(xb + n * WW + p * 64);
            float a = 0.f;
#pragma unroll
            for (int i = 0; i < 16; ++i) {
                f4t v = xr[i], l4 = lu4[i];
                a = fmaf(v.x, l4.x, a); a = fmaf(v.y, l4.y, a);
                a = fmaf(v.z, l4.z, a); a = fmaf(v.w, l4.w, a);
            }
            a += __shfl_xor(a, 1, 64);
            float val = (a + lub_o) * CLOG;
            float vn  = __shfl_xor(val, 2, 64);
            if (!(tid & 3)) s_pool[n * 64 + ((tid >> 2) ^ (n & 31))] = pk2(val, vn);
        }
    }
    __syncthreads();
    __builtin_amdgcn_sched_barrier(0);   // keep weight loads below phase A's lu4 transient

    float elvsum;
    {
        const f2t lvp = *(const f2t*)&s_wlvf[(tid & 63) * 4 + 2];
        elvsum = wsum(lvp.x + lvp.y);
    }

    // ---------------- encoder weights -> fp16-pair registers (+ LDS "spill") ----
    h2t lw_r[32];
    {
        const f2t* r = (const f2t*)(elw + (tid >> 1) * 128 + (tid & 1) * 64);
#pragma unroll
        for (int i = 0; i < 32; ++i) { f2t v = r[i]; lw_r[i] = pk2(v.x, v.y); }
    }
    const float lwb_r = elwb[tid >> 1];
    h2t wih_r[44];
    {
        const f2t* r = (const f2t*)(eWih + jrow * 96);
#pragma unroll
        for (int i = 0; i < 44; ++i) { f2t v = r[i]; wih_r[i] = pk2(v.x, v.y); }
        f4t ws;
        { f2t v = r[44]; ws.x = bcf(pk2(v.x, v.y)); }
        { f2t v = r[45]; ws.y = bcf(pk2(v.x, v.y)); }
        { f2t v = r[46]; ws.z = bcf(pk2(v.x, v.y)); }
        { f2t v = r[47]; ws.w = bcf(pk2(v.x, v.y)); }
        s_spillw[tid] = ws;
    }
    h2t whh_r[24];
    {
        const f2t* r = (const f2t*)(eWhh + jrow * 64);
#pragma unroll
        for (int i = 0; i < 24; ++i) { f2t v = r[i]; whh_r[i] = pk2(v.x, v.y); }
        f4t w0, w1;
        { f2t v = r[24]; w0.x = bcf(pk2(v.x, v.y)); }
        { f2t v = r[25]; w0.y = bcf(pk2(v.x, v.y)); }
        { f2t v = r[26]; w0.z = bcf(pk2(v.x, v.y)); }
        { f2t v = r[27]; w0.w = bcf(pk2(v.x, v.y)); }
        { f2t v = r[28]; w1.x = bcf(pk2(v.x, v.y)); }
        { f2t v = r[29]; w1.y = bcf(pk2(v.x, v.y)); }
        { f2t v = r[30]; w1.z = bcf(pk2(v.x, v.y)); }
        { f2t v = r[31]; w1.w = bcf(pk2(v.x, v.y)); }
        s_spillh[0][tid] = w0;
        s_spillh[1][tid] = w1;
    }
    const float bsum_r = ebih[jrow] + ebhh[jrow];
    __builtin_amdgcn_sched_barrier(0);

    // ---------------- encoder recurrence: 4 barriers/step ----
#pragma unroll 1
    for (int t = 0; t < WW; ++t) {
        const int pp = t & 1;
        // ph1: w_out via pair-split + shfl combine; prefetch x column
        float xv = 0.f;
        if (!(tid & 1) && tid < 192) xv = xb[(tid >> 1) * WW + t];
        {
            const f4t* hc4 = (const f4t*)&s_hch2[pp][(tid & 1) * 32];
            float a = 0.f;
#pragma unroll
            for (int i = 0; i < 8; ++i) { f4t v = hc4[i]; DOT4(v, lw_r, 4 * i, a); }
            a += __shfl_xor(a, 1, 64);
            float wo = (a + lwb_r) * CLOG;
            float wn = __shfl_xor(wo, 2, 64);
            if (!(tid & 3)) { f2t st = {wo, wn}; *(f2t*)&s_wlvf[(tid >> 2) * 4] = st; }
        }
        __syncthreads();
        // ph2: scores (tanh trick) + exp, shfl-combined
        float prod = 0.f;
        if (tid < 192) {
            const int n = tid >> 1, sw = n & 31;
            const h2t* uer = s_pool + n * 64;
            float a = 0.f;
#pragma unroll
            for (int j = 0; j < 32; ++j) {
                const int wp = (tid & 1) * 32 + j;
                f4t wl = s_wlv[wp];
                h2t u  = uer[wp ^ sw];
                float r0 = rcp_(ex2(wl.x + (float)u.x) + 1.f);
                float r1 = rcp_(ex2(wl.y + (float)u.y) + 1.f);
                a = fmaf(wl.z, r0, a);
                a = fmaf(wl.w, r1, a);
            }
            a += __shfl_xor(a, 1, 64);
            if (!(tid & 1)) {
                float e = ex2((elvsum - 2.f * a) * L2E);
                prod = e * xv;
                s_soft[n] = e;
            }
        }
        __syncthreads();
        // ph3: normalize + x_tilde
        if (tid < 192) {
            const int l = tid & 63;
            float sm = s_soft[l] + s_soft[64 + l];   // [96..127] are zeros
            sm = wsum(sm);
            float inv = rcp_(sm);
            float p1 = __shfl_xor(prod, 2, 64);
            if (!(tid & 3)) s_xt[tid >> 2] = pk2(prod * inv, p1 * inv);
        }
        __syncthreads();
        // ph4: gates + fused LSTM update (quad-gate layout)
        {
            float gv = bsum_r;
            const f4t* xt4 = (const f4t*)s_xt;
#pragma unroll
            for (int i = 0; i < 11; ++i) { f4t v = xt4[i]; DOT4(v, wih_r, 4 * i, gv); }
            { f4t v = xt4[11]; f4t w = s_spillw[tid]; DOT4W(v, w, gv); }
            const f4t* h4 = (const f4t*)&s_hch2[pp][0];
#pragma unroll
            for (int i = 0; i < 6; ++i) { f4t v = h4[i]; DOT4(v, whh_r, 4 * i, gv); }
            { f4t v = h4[6]; f4t w = s_spillh[0][tid]; DOT4W(v, w, gv); }
            { f4t v = h4[7]; f4t w = s_spillh[1][tid]; DOT4W(v, w, gv); }
            const int base = lane & ~3;
            float gi = __shfl(gv, base, 64);
            float gf = __shfl(gv, base + 1, 64);
            float g2 = __shfl(gv, base + 2, 64);
            float go = __shfl(gv, base + 3, 64);
            float c = sig_c(gf) * c_reg + sig_c(gi) * tanh_c(g2);
            float h = sig_c(go) * tanh_c(c);
            c_reg = c;
            float hn = __shfl_xor(h, 4, 64);
            float cn = __shfl_xor(c, 4, 64);
            if (!(lane & 7)) {
                const int k = wq * 8 + (lane >> 3);
                s_hch2[pp ^ 1][k]      = pk2(h, hn);
                s_hch2[pp ^ 1][32 + k] = pk2(c, cn);
                if constexpr (HSG) hsgb[t * 32 + k] = pk2(h, hn);
                else               s_hseq2[t][k ^ (t & 31)] = pk2(h, hn);
            }
        }
        __syncthreads();
    }

    // ---------------- u_d = h_seq @ dlu^T + dlub (scaled fp16, swizzled into pool) ----
    {
        const int e2h = tid & 31;
        h2t du0[32], du1[32];
        {
            const f4t* p0 = (const f4t*)(dlu + (2 * e2h) * 64);
            const f4t* p1 = (const f4t*)(dlu + (2 * e2h + 1) * 64);
#pragma unroll
            for (int i = 0; i < 16; ++i) {
                f4t v0 = p0[i], v1 = p1[i];
                du0[2 * i] = pk2(v0.x, v0.y); du0[2 * i + 1] = pk2(v0.z, v0.w);
                du1[2 * i] = pk2(v1.x, v1.y); du1[2 * i + 1] = pk2(v1.z, v1.w);
            }
        }
        const float b0 = dlub[2 * e2h], b1 = dlub[2 * e2h + 1];
#pragma unroll 1
        for (int pass = 0; pass < 16; ++pass) {
            const int w = pass * 8 + (tid >> 5);
            float a0 = b0, a1 = b1;
            if constexpr (HSG) {
                const f4t* hr = (const f4t*)(hsgb + w * 32);
#pragma unroll
                for (int i = 0; i < 8; ++i) {
                    f4t v = hr[i];
                    DOT4(v, du0, 4 * i, a0);
                    DOT4(v, du1, 4 * i, a1);
                }
            } else {
                const int sww = w & 31;
#pragma unroll
                for (int i = 0; i < 32; ++i) {
                    h2t hp = s_hseq2[w][i ^ sww];
                    a0 = fdot2(hp, du0[i], a0);
                    a1 = fdot2(hp, du1[i], a1);
                }
            }
            s_pool[w * 32 + (e2h ^ (w & 31))] = pk2(a0 * CLOG, a1 * CLOG);
        }
    }
    __builtin_amdgcn_sched_barrier(0);   // keep decoder weight loads below u_d's du0/du1 transient

    // ---------------- decoder setup ----------------
    const int tgt = tgtp[0];
    if (tid < 32) {
        s_wlvf[tid * 4 + 2] = dlv[2 * tid];
        s_wlvf[tid * 4 + 3] = dlv[2 * tid + 1];
    }
    if (tid < 64) s_hch2[0][tid] = pk2(0.f, 0.f);
    float dlvsum;
    { float v = dlv[tid & 63]; dlvsum = wsum(v); }
    h2t dlw_r[16];
    {
        const f2t* r = (const f2t*)(dlw + (tid >> 2) * 128 + (tid & 3) * 32);
#pragma unroll
        for (int i = 0; i < 16; ++i) { f2t v = r[i]; dlw_r[i] = pk2(v.x, v.y); }
    }
    const float dlwb_r = dlwb[tid >> 2];
    h2t dwhh_r[32];
    {
        const f2t* r = (const f2t*)(dWhh + jrow * 64);
#pragma unroll
        for (int i = 0; i < 32; ++i) { f2t v = r[i]; dwhh_r[i] = pk2(v.x, v.y); }
    }
    const float dwih_r  = dWih[jrow];
    const float dbsum_r = dbih[jrow] + dbhh[jrow];
    const float lp0     = dlp[0];
    const float lp1_r   = dlp[1 + (tid & 63)];
    const float lpb     = dlpb[0];
    c_reg = 0.f;
    float h_reg = 0.f;
    __syncthreads();

    // ---------------- decoder recurrence: 4 barriers/step ----
#pragma unroll 1
    for (int s = 0; s < WW - 1; ++s) {
        const int pp = s & 1;
        const float ys = xb[(size_t)tgt * WW + s];
        // ph1: w_out_d via quad-split + shfl
        {
            const f4t* hc4 = (const f4t*)&s_hch2[pp][(tid & 3) * 16];
            float a = 0.f;
#pragma unroll
            for (int i = 0; i < 4; ++i) { f4t v = hc4[i]; DOT4(v, dlw_r, 4 * i, a); }
            a += __shfl_xor(a, 1, 64);
            a += __shfl_xor(a, 2, 64);
            float wo = (a + dlwb_r) * CLOG;
            float wn = __shfl_xor(wo, 4, 64);
            if (!(tid & 7)) { f2t st = {wo, wn}; *(f2t*)&s_wlvf[(tid >> 3) * 4] = st; }
        }
        __syncthreads();
        // ph2: v scores + exp
        {
            const int w = tid >> 1, sw = w & 31;
            const h2t* udr = s_pool + w * 32;
            float a = 0.f;
#pragma unroll
            for (int j = 0; j < 16; ++j) {
                const int ep = (tid & 1) * 16 + j;
                f4t wl = s_wlv[ep];
                h2t u  = udr[ep ^ sw];
                float r0 = rcp_(ex2(wl.x + (float)u.x) + 1.f);
                float r1 = rcp_(ex2(wl.y + (float)u.y) + 1.f);
                a = fmaf(wl.z, r0, a);
                a = fmaf(wl.w, r1, a);
            }
            a += __shfl_xor(a, 1, 64);
            if (!(tid & 1)) s_soft[w] = ex2((dlvsum - 2.f * a) * L2E);
        }
        __syncthreads();
        // ph3: inv + context partials
        float inv;
        {
            const int l = tid & 63;
            float sm = s_soft[l] + s_soft[64 + l];
            sm = wsum(sm);
            inv = rcp_(sm);
            const int e2 = tid & 31, pg = tid >> 5;
            float a0 = 0.f, a1 = 0.f;
#pragma unroll
            for (int j = 0; j < 16; ++j) {
                const int w = pg * 16 + j;
                float bw = s_soft[w];
                h2t hp;
                if constexpr (HSG) hp = hsgb[w * 32 + e2];
                else               hp = s_hseq2[w][e2 ^ (w & 31)];
                a0 = fmaf(bw, (float)hp.x, a0);
                a1 = fmaf(bw, (float)hp.y, a1);
            }
            a0 += __shfl_xor(a0, 32, 64);
            a1 += __shfl_xor(a1, 32, 64);
            if ((tid & 63) < 32) { f2t st = {a0, a1}; *(f2t*)&s_tmp[wq * 64 + e2 * 2] = st; }
        }
        __syncthreads();
        // ph4: y_tilde (redundant) + gates + fused update
        {
            const int l = tid & 63;
            float ctx = s_tmp[l] + s_tmp[64 + l] + s_tmp[128 + l] + s_tmp[192 + l];
            float term = ctx * inv * lp1_r;
            term = wsum(term);
            float yt = fmaf(ys, lp0, term + lpb);
            float gv = fmaf(yt, dwih_r, dbsum_r);
            const f4t* h4 = (const f4t*)&s_hch2[pp][0];
#pragma unroll
            for (int i = 0; i < 8; ++i) { f4t v = h4[i]; DOT4(v, dwhh_r, 4 * i, gv); }
            const int base = l & ~3;
            float gi = __shfl(gv, base, 64);
            float gf = __shfl(gv, base + 1, 64);
            float g2 = __shfl(gv, base + 2, 64);
            float go = __shfl(gv, base + 3, 64);
            float c = sig_c(gf) * c_reg + sig_c(gi) * tanh_c(g2);
            float h = sig_c(go) * tanh_c(c);
            c_reg = c; h_reg = h;
            float hn = __shfl_xor(h, 4, 64);
            float cn = __shfl_xor(c, 4, 64);
            if (!(l & 7)) {
                const int k = wq * 8 + (l >> 3);
                s_hch2[pp ^ 1][k]      = pk2(h, hn);
                s_hch2[pp ^ 1][32 + k] = pk2(c, cn);
            }
        }
        __syncthreads();
    }

    // ---------------- output: out[b] = [h,c] . dly + dlyb ----------------
    {
        float term = 0.f;
        if (!(lane & 3)) term = h_reg * dly[uidx] + c_reg * dly[64 + uidx];
        term = wsum(term);
        if (lane == 0) s_tmp[wq] = term;
    }
    __syncthreads();
    if (tid == 0) out[b] = s_tmp[0] + s_tmp[1] + s_tmp[2] + s_tmp[3] + dlyb[0];
}

extern "C" void kernel_launch(void* const* d_in, const int* in_sizes, int n_in,
                              void* d_out, int out_size, void* d_ws, size_t ws_size,
                              hipStream_t stream) {
    (void)in_sizes; (void)n_in; (void)out_size;
    const float* x    = (const float*)d_in[0];
    const float* eWih = (const float*)d_in[1];
    const float* eWhh = (const float*)d_in[2];
    const float* ebih = (const float*)d_in[3];
    const float* ebhh = (const float*)d_in[4];
    const float* elv  = (const float*)d_in[5];
    const float* elw  = (const float*)d_in[6];
    const float* elwb = (const float*)d_in[7];
    const float* elu  = (const float*)d_in[8];
    const float* elub = (const float*)d_in[9];
    const float* dWih = (const float*)d_in[10];
    const float* dWhh = (const float*)d_in[11];
    const float* dbih = (const float*)d_in[12];
    const float* dbhh = (const float*)d_in[13];
    const float* dlv  = (const float*)d_in[14];
    const float* dlw  = (const float*)d_in[15];
    const float* dlwb = (const float*)d_in[16];
    const float* dlu  = (const float*)d_in[17];
    const float* dlub = (const float*)d_in[18];
    const float* dlp  = (const float*)d_in[19];
    const float* dlpb = (const float*)d_in[20];
    const float* dly  = (const float*)d_in[21];
    const float* dlyb = (const float*)d_in[22];
    const int*   tgt  = (const int*)d_in[23];
    float* out = (float*)d_out;

    const size_t need = (size_t)NB * WW * 32 * sizeof(h2t);  // 16 MiB
    if (d_ws && ws_size >= need) {
        darnn_kernel<true><<<NB, 256, 0, stream>>>(
            x, eWih, eWhh, ebih, ebhh, elv, elw, elwb, elu, elub,
            dWih, dWhh, dbih, dbhh, dlv, dlw, dlwb, dlu, dlub,
            dlp, dlpb, dly, dlyb, tgt, (h2t*)d_ws, out);
    } else {
        darnn_kernel<false><<<NB, 256, 0, stream>>>(
            x, eWih, eWhh, ebih, ebhh, elv, elw, elwb, elu, elub,
            dWih, dWhh, dbih, dbhh, dlv, dlw, dlwb, dlu, dlub,
            dlp, dlpb, dly, dlyb, tgt, (h2t*)nullptr, out);
    }
}

// Round 4
// 1814.882 us; speedup vs baseline: 2.1322x; 2.0968x over previous
//
#include <hip/hip_runtime.h>

#define NB 1024
#define NV 96
#define WW 128
#define EE 64
#define DD 64

typedef _Float16 h2t __attribute__((ext_vector_type(2)));
typedef float f2t __attribute__((ext_vector_type(2)));
typedef float f4t __attribute__((ext_vector_type(4)));

#define CLOG 2.885390081777927f   /* 2*log2(e) */
#define L2E  1.4426950408889634f  /* log2(e)   */

__device__ __forceinline__ float fdot2(h2t a, h2t b, float c) {
    return __builtin_amdgcn_fdot2(a, b, c, false);
}
__device__ __forceinline__ h2t pk2(float a, float b) {
    h2t r; r.x = (_Float16)a; r.y = (_Float16)b; return r;
}
__device__ __forceinline__ h2t bch(float f) { return __builtin_bit_cast(h2t, f); }
__device__ __forceinline__ float bcf(h2t p) { return __builtin_bit_cast(float, p); }
__device__ __forceinline__ float ex2(float x) { return __builtin_amdgcn_exp2f(x); }
__device__ __forceinline__ float rcp_(float x) { return __builtin_amdgcn_rcpf(x); }
__device__ __forceinline__ float sig_c(float x) { return rcp_(1.f + ex2(-x * L2E)); }
__device__ __forceinline__ float tanh_c(float x) { return 1.f - 2.f * rcp_(ex2(x * CLOG) + 1.f); }
__device__ __forceinline__ float wsum(float v) {
#pragma unroll
    for (int o = 32; o; o >>= 1) v += __shfl_xor(v, o, 64);
    return v;
}

// 4 fdot2 from one f4 of packed-half pairs
#define DOT4(V, WR, B, ACC) do { \
    ACC = fdot2(bch((V).x), (WR)[(B) + 0], ACC); \
    ACC = fdot2(bch((V).y), (WR)[(B) + 1], ACC); \
    ACC = fdot2(bch((V).z), (WR)[(B) + 2], ACC); \
    ACC = fdot2(bch((V).w), (WR)[(B) + 3], ACC); } while (0)

// dot a f4 of activation-pairs with a f4 of LDS-held weight-pairs
#define DOT4W(V, W4, ACC) do { \
    ACC = fdot2(bch((V).x), bch((W4).x), ACC); \
    ACC = fdot2(bch((V).y), bch((W4).y), ACC); \
    ACC = fdot2(bch((V).z), bch((W4).z), ACC); \
    ACC = fdot2(bch((V).w), bch((W4).w), ACC); } while (0)

template<bool HSG>
__global__ __launch_bounds__(256, 2)   // r1-proven register contract: VGPR ~124, no scratch
void darnn_kernel(
    const float* __restrict__ x,
    const float* __restrict__ eWih, const float* __restrict__ eWhh,
    const float* __restrict__ ebih, const float* __restrict__ ebhh,
    const float* __restrict__ elv,  const float* __restrict__ elw,
    const float* __restrict__ elwb, const float* __restrict__ elu,
    const float* __restrict__ elub,
    const float* __restrict__ dWih, const float* __restrict__ dWhh,
    const float* __restrict__ dbih, const float* __restrict__ dbhh,
    const float* __restrict__ dlv,  const float* __restrict__ dlw,
    const float* __restrict__ dlwb, const float* __restrict__ dlu,
    const float* __restrict__ dlub, const float* __restrict__ dlp,
    const float* __restrict__ dlpb, const float* __restrict__ dly,
    const float* __restrict__ dlyb, const int* __restrict__ tgtp,
    h2t* __restrict__ hsg_all,
    float* __restrict__ out)
{
    // u_e: h2t[96][64] XOR-swizzled (scaled by CLOG) | later u_d: h2t[128][32] swizzled
    __shared__ __align__(16) h2t  s_pool[96 * 64];                 // 24576 B
    __shared__ __align__(16) h2t  s_hseq2[HSG ? 1 : WW][32];       // fallback h_seq
    __shared__ __align__(16) f4t  s_wlv[64];                       // 1024 B {wo0*C, wo1*C, lv0, lv1}
    __shared__ __align__(16) char s_u2[1024];                      // enc: s_xt h2t[48] | dec: s_tmp f[256]
    __shared__ __align__(16) float s_soft[128];                    // 512 B
    __shared__ __align__(16) h2t  s_hch2[2][64];                   // 512 B double-buffered [h,c] pairs
    __shared__ __align__(16) f4t  s_spillh[2][256];                // 8192 B  eWhh pairs 24..31 (per tid)
    __shared__ __align__(16) f4t  s_spillw[256];                   // 4096 B  eWih pairs 44..47 (per tid)

    float* s_wlvf = (float*)s_wlv;
    h2t*  const s_xt  = (h2t*)s_u2;
    float* const s_tmp = (float*)s_u2;

    const int tid  = threadIdx.x;
    const int b    = blockIdx.x;
    const int lane = tid & 63, wq = tid >> 6;
    const int uidx = wq * 16 + (lane >> 2);      // unit owned (redundant x4)
    const int jrow = (lane & 3) * 64 + uidx;     // gate row owned
    const float* xb = x + (size_t)b * NV * WW;
    h2t* hsgb = HSG ? (hsg_all + (size_t)b * (WW * 32)) : (h2t*)nullptr;

    float c_reg = 0.f;

    // ---------------- init ----------------
    if (tid >= 96 && tid < 128) s_soft[tid] = 0.f;
    if (tid < 64) {
        s_hch2[0][tid] = pk2(0.f, 0.f);
        s_wlvf[tid * 4 + 2] = elv[2 * tid];
        s_wlvf[tid * 4 + 3] = elv[2 * tid + 1];
    }

    // ---------------- phase A: u_e (scaled, fp16, swizzled), barrier-free ----
    {
        const int o = tid >> 1, p = tid & 1;
        f4t lu4[16];
        const f4t* lur = (const f4t*)(elu + o * WW + p * 64);
#pragma unroll
        for (int i = 0; i < 16; ++i) lu4[i] = lur[i];
        const float lub_o = elub[o];
        for (int n = 0; n < NV; ++n) {
            const f4t* xr = (const f4t*)(xb + n * WW + p * 64);
            float a = 0.f;
#pragma unroll
            for (int i = 0; i < 16; ++i) {
                f4t v = xr[i], l4 = lu4[i];
                a = fmaf(v.x, l4.x, a); a = fmaf(v.y, l4.y, a);
                a = fmaf(v.z, l4.z, a); a = fmaf(v.w, l4.w, a);
            }
            a += __shfl_xor(a, 1, 64);
            float val = (a + lub_o) * CLOG;
            float vn  = __shfl_xor(val, 2, 64);
            if (!(tid & 3)) s_pool[n * 64 + ((tid >> 2) ^ (n & 31))] = pk2(val, vn);
        }
    }
    __syncthreads();
    __builtin_amdgcn_sched_barrier(0);   // keep weight loads below phase A's lu4 transient

    float elvsum;
    {
        const f2t lvp = *(const f2t*)&s_wlvf[(tid & 63) * 4 + 2];
        elvsum = wsum(lvp.x + lvp.y);
    }

    // ---------------- encoder weights -> fp16-pair registers (+ LDS "spill") ----
    h2t lw_r[32];
    {
        const f2t* r = (const f2t*)(elw + (tid >> 1) * 128 + (tid & 1) * 64);
#pragma unroll
        for (int i = 0; i < 32; ++i) { f2t v = r[i]; lw_r[i] = pk2(v.x, v.y); }
    }
    const float lwb_r = elwb[tid >> 1];
    h2t wih_r[44];
    {
        const f2t* r = (const f2t*)(eWih + jrow * 96);
#pragma unroll
        for (int i = 0; i < 44; ++i) { f2t v = r[i]; wih_r[i] = pk2(v.x, v.y); }
        f4t ws;
        { f2t v = r[44]; ws.x = bcf(pk2(v.x, v.y)); }
        { f2t v = r[45]; ws.y = bcf(pk2(v.x, v.y)); }
        { f2t v = r[46]; ws.z = bcf(pk2(v.x, v.y)); }
        { f2t v = r[47]; ws.w = bcf(pk2(v.x, v.y)); }
        s_spillw[tid] = ws;
    }
    h2t whh_r[24];
    {
        const f2t* r = (const f2t*)(eWhh + jrow * 64);
#pragma unroll
        for (int i = 0; i < 24; ++i) { f2t v = r[i]; whh_r[i] = pk2(v.x, v.y); }
        f4t w0, w1;
        { f2t v = r[24]; w0.x = bcf(pk2(v.x, v.y)); }
        { f2t v = r[25]; w0.y = bcf(pk2(v.x, v.y)); }
        { f2t v = r[26]; w0.z = bcf(pk2(v.x, v.y)); }
        { f2t v = r[27]; w0.w = bcf(pk2(v.x, v.y)); }
        { f2t v = r[28]; w1.x = bcf(pk2(v.x, v.y)); }
        { f2t v = r[29]; w1.y = bcf(pk2(v.x, v.y)); }
        { f2t v = r[30]; w1.z = bcf(pk2(v.x, v.y)); }
        { f2t v = r[31]; w1.w = bcf(pk2(v.x, v.y)); }
        s_spillh[0][tid] = w0;
        s_spillh[1][tid] = w1;
    }
    const float bsum_r = ebih[jrow] + ebhh[jrow];
    __builtin_amdgcn_sched_barrier(0);

    // ---------------- encoder recurrence: 4 barriers/step ----
#pragma unroll 1
    for (int t = 0; t < WW; ++t) {
        const int pp = t & 1;
        // ph1: w_out via pair-split + shfl combine; prefetch x column
        float xv = 0.f;
        if (!(tid & 1) && tid < 192) xv = xb[(tid >> 1) * WW + t];
        {
            const f4t* hc4 = (const f4t*)&s_hch2[pp][(tid & 1) * 32];
            float a = 0.f;
#pragma unroll
            for (int i = 0; i < 8; ++i) { f4t v = hc4[i]; DOT4(v, lw_r, 4 * i, a); }
            a += __shfl_xor(a, 1, 64);
            float wo = (a + lwb_r) * CLOG;
            float wn = __shfl_xor(wo, 2, 64);
            if (!(tid & 3)) { f2t st = {wo, wn}; *(f2t*)&s_wlvf[(tid >> 2) * 4] = st; }
        }
        __syncthreads();
        // ph2: scores (tanh trick) + exp, shfl-combined
        float prod = 0.f;
        if (tid < 192) {
            const int n = tid >> 1, sw = n & 31;
            const h2t* uer = s_pool + n * 64;
            float a = 0.f;
#pragma unroll
            for (int j = 0; j < 32; ++j) {
                const int wp = (tid & 1) * 32 + j;
                f4t wl = s_wlv[wp];
                h2t u  = uer[wp ^ sw];
                float r0 = rcp_(ex2(wl.x + (float)u.x) + 1.f);
                float r1 = rcp_(ex2(wl.y + (float)u.y) + 1.f);
                a = fmaf(wl.z, r0, a);
                a = fmaf(wl.w, r1, a);
            }
            a += __shfl_xor(a, 1, 64);
            if (!(tid & 1)) {
                float e = ex2((elvsum - 2.f * a) * L2E);
                prod = e * xv;
                s_soft[n] = e;
            }
        }
        __syncthreads();
        // ph3: normalize + x_tilde
        if (tid < 192) {
            const int l = tid & 63;
            float sm = s_soft[l] + s_soft[64 + l];   // [96..127] are zeros
            sm = wsum(sm);
            float inv = rcp_(sm);
            float p1 = __shfl_xor(prod, 2, 64);
            if (!(tid & 3)) s_xt[tid >> 2] = pk2(prod * inv, p1 * inv);
        }
        __syncthreads();
        // ph4: gates + fused LSTM update (quad-gate layout)
        {
            float gv = bsum_r;
            const f4t* xt4 = (const f4t*)s_xt;
#pragma unroll
            for (int i = 0; i < 11; ++i) { f4t v = xt4[i]; DOT4(v, wih_r, 4 * i, gv); }
            { f4t v = xt4[11]; f4t w = s_spillw[tid]; DOT4W(v, w, gv); }
            const f4t* h4 = (const f4t*)&s_hch2[pp][0];
#pragma unroll
            for (int i = 0; i < 6; ++i) { f4t v = h4[i]; DOT4(v, whh_r, 4 * i, gv); }
            { f4t v = h4[6]; f4t w = s_spillh[0][tid]; DOT4W(v, w, gv); }
            { f4t v = h4[7]; f4t w = s_spillh[1][tid]; DOT4W(v, w, gv); }
            const int base = lane & ~3;
            float gi = __shfl(gv, base, 64);
            float gf = __shfl(gv, base + 1, 64);
            float g2 = __shfl(gv, base + 2, 64);
            float go = __shfl(gv, base + 3, 64);
            float c = sig_c(gf) * c_reg + sig_c(gi) * tanh_c(g2);
            float h = sig_c(go) * tanh_c(c);
            c_reg = c;
            float hn = __shfl_xor(h, 4, 64);
            float cn = __shfl_xor(c, 4, 64);
            if (!(lane & 7)) {
                const int k = wq * 8 + (lane >> 3);
                s_hch2[pp ^ 1][k]      = pk2(h, hn);
                s_hch2[pp ^ 1][32 + k] = pk2(c, cn);
                if constexpr (HSG) hsgb[t * 32 + k] = pk2(h, hn);
                else               s_hseq2[t][k ^ (t & 31)] = pk2(h, hn);
            }
        }
        __syncthreads();
    }

    // ---------------- u_d = h_seq @ dlu^T + dlub (scaled fp16, swizzled into pool) ----
    {
        const int e2h = tid & 31;
        h2t du0[32], du1[32];
        {
            const f4t* p0 = (const f4t*)(dlu + (2 * e2h) * 64);
            const f4t* p1 = (const f4t*)(dlu + (2 * e2h + 1) * 64);
#pragma unroll
            for (int i = 0; i < 16; ++i) {
                f4t v0 = p0[i], v1 = p1[i];
                du0[2 * i] = pk2(v0.x, v0.y); du0[2 * i + 1] = pk2(v0.z, v0.w);
                du1[2 * i] = pk2(v1.x, v1.y); du1[2 * i + 1] = pk2(v1.z, v1.w);
            }
        }
        const float b0 = dlub[2 * e2h], b1 = dlub[2 * e2h + 1];
#pragma unroll 1
        for (int pass = 0; pass < 16; ++pass) {
            const int w = pass * 8 + (tid >> 5);
            float a0 = b0, a1 = b1;
            if constexpr (HSG) {
                const f4t* hr = (const f4t*)(hsgb + w * 32);
#pragma unroll
                for (int i = 0; i < 8; ++i) {
                    f4t v = hr[i];
                    DOT4(v, du0, 4 * i, a0);
                    DOT4(v, du1, 4 * i, a1);
                }
            } else {
                const int sww = w & 31;
#pragma unroll
                for (int i = 0; i < 32; ++i) {
                    h2t hp = s_hseq2[w][i ^ sww];
                    a0 = fdot2(hp, du0[i], a0);
                    a1 = fdot2(hp, du1[i], a1);
                }
            }
            s_pool[w * 32 + (e2h ^ (w & 31))] = pk2(a0 * CLOG, a1 * CLOG);
        }
    }
    __builtin_amdgcn_sched_barrier(0);   // keep decoder weight loads below u_d's du0/du1 transient

    // ---------------- decoder setup ----------------
    const int tgt = tgtp[0];
    if (tid < 32) {
        s_wlvf[tid * 4 + 2] = dlv[2 * tid];
        s_wlvf[tid * 4 + 3] = dlv[2 * tid + 1];
    }
    if (tid < 64) s_hch2[0][tid] = pk2(0.f, 0.f);
    float dlvsum;
    { float v = dlv[tid & 63]; dlvsum = wsum(v); }
    h2t dlw_r[16];
    {
        const f2t* r = (const f2t*)(dlw + (tid >> 2) * 128 + (tid & 3) * 32);
#pragma unroll
        for (int i = 0; i < 16; ++i) { f2t v = r[i]; dlw_r[i] = pk2(v.x, v.y); }
    }
    const float dlwb_r = dlwb[tid >> 2];
    h2t dwhh_r[32];
    {
        const f2t* r = (const f2t*)(dWhh + jrow * 64);
#pragma unroll
        for (int i = 0; i < 32; ++i) { f2t v = r[i]; dwhh_r[i] = pk2(v.x, v.y); }
    }
    const float dwih_r  = dWih[jrow];
    const float dbsum_r = dbih[jrow] + dbhh[jrow];
    const float lp0     = dlp[0];
    const float lp1_r   = dlp[1 + (tid & 63)];
    const float lpb     = dlpb[0];
    c_reg = 0.f;
    float h_reg = 0.f;
    __syncthreads();

    // ---------------- decoder recurrence: 4 barriers/step ----
#pragma unroll 1
    for (int s = 0; s < WW - 1; ++s) {
        const int pp = s & 1;
        const float ys = xb[(size_t)tgt * WW + s];
        // ph1: w_out_d via quad-split + shfl
        {
            const f4t* hc4 = (const f4t*)&s_hch2[pp][(tid & 3) * 16];
            float a = 0.f;
#pragma unroll
            for (int i = 0; i < 4; ++i) { f4t v = hc4[i]; DOT4(v, dlw_r, 4 * i, a); }
            a += __shfl_xor(a, 1, 64);
            a += __shfl_xor(a, 2, 64);
            float wo = (a + dlwb_r) * CLOG;
            float wn = __shfl_xor(wo, 4, 64);
            if (!(tid & 7)) { f2t st = {wo, wn}; *(f2t*)&s_wlvf[(tid >> 3) * 4] = st; }
        }
        __syncthreads();
        // ph2: v scores + exp
        {
            const int w = tid >> 1, sw = w & 31;
            const h2t* udr = s_pool + w * 32;
            float a = 0.f;
#pragma unroll
            for (int j = 0; j < 16; ++j) {
                const int ep = (tid & 1) * 16 + j;
                f4t wl = s_wlv[ep];
                h2t u  = udr[ep ^ sw];
                float r0 = rcp_(ex2(wl.x + (float)u.x) + 1.f);
                float r1 = rcp_(ex2(wl.y + (float)u.y) + 1.f);
                a = fmaf(wl.z, r0, a);
                a = fmaf(wl.w, r1, a);
            }
            a += __shfl_xor(a, 1, 64);
            if (!(tid & 1)) s_soft[w] = ex2((dlvsum - 2.f * a) * L2E);
        }
        __syncthreads();
        // ph3: inv + context partials
        float inv;
        {
            const int l = tid & 63;
            float sm = s_soft[l] + s_soft[64 + l];
            sm = wsum(sm);
            inv = rcp_(sm);
            const int e2 = tid & 31, pg = tid >> 5;
            float a0 = 0.f, a1 = 0.f;
#pragma unroll
            for (int j = 0; j < 16; ++j) {
                const int w = pg * 16 + j;
                float bw = s_soft[w];
                h2t hp;
                if constexpr (HSG) hp = hsgb[w * 32 + e2];
                else               hp = s_hseq2[w][e2 ^ (w & 31)];
                a0 = fmaf(bw, (float)hp.x, a0);
                a1 = fmaf(bw, (float)hp.y, a1);
            }
            a0 += __shfl_xor(a0, 32, 64);
            a1 += __shfl_xor(a1, 32, 64);
            if ((tid & 63) < 32) { f2t st = {a0, a1}; *(f2t*)&s_tmp[wq * 64 + e2 * 2] = st; }
        }
        __syncthreads();
        // ph4: y_tilde (redundant) + gates + fused update
        {
            const int l = tid & 63;
            float ctx = s_tmp[l] + s_tmp[64 + l] + s_tmp[128 + l] + s_tmp[192 + l];
            float term = ctx * inv * lp1_r;
            term = wsum(term);
            float yt = fmaf(ys, lp0, term + lpb);
            float gv = fmaf(yt, dwih_r, dbsum_r);
            const f4t* h4 = (const f4t*)&s_hch2[pp][0];
#pragma unroll
            for (int i = 0; i < 8; ++i) { f4t v = h4[i]; DOT4(v, dwhh_r, 4 * i, gv); }
            const int base = l & ~3;
            float gi = __shfl(gv, base, 64);
            float gf = __shfl(gv, base + 1, 64);
            float g2 = __shfl(gv, base + 2, 64);
            float go = __shfl(gv, base + 3, 64);
            float c = sig_c(gf) * c_reg + sig_c(gi) * tanh_c(g2);
            float h = sig_c(go) * tanh_c(c);
            c_reg = c; h_reg = h;
            float hn = __shfl_xor(h, 4, 64);
            float cn = __shfl_xor(c, 4, 64);
            if (!(l & 7)) {
                const int k = wq * 8 + (l >> 3);
                s_hch2[pp ^ 1][k]      = pk2(h, hn);
                s_hch2[pp ^ 1][32 + k] = pk2(c, cn);
            }
        }
        __syncthreads();
    }

    // ---------------- output: out[b] = [h,c] . dly + dlyb ----------------
    {
        float term = 0.f;
        if (!(lane & 3)) term = h_reg * dly[uidx] + c_reg * dly[64 + uidx];
        term = wsum(term);
        if (lane == 0) s_tmp[wq] = term;
    }
    __syncthreads();
    if (tid == 0) out[b] = s_tmp[0] + s_tmp[1] + s_tmp[2] + s_tmp[3] + dlyb[0];
}

extern "C" void kernel_launch(void* const* d_in, const int* in_sizes, int n_in,
                              void* d_out, int out_size, void* d_ws, size_t ws_size,
                              hipStream_t stream) {
    (void)in_sizes; (void)n_in; (void)out_size;
    const float* x    = (const float*)d_in[0];
    const float* eWih = (const float*)d_in[1];
    const float* eWhh = (const float*)d_in[2];
    const float* ebih = (const float*)d_in[3];
    const float* ebhh = (const float*)d_in[4];
    const float* elv  = (const float*)d_in[5];
    const float* elw  = (const float*)d_in[6];
    const float* elwb = (const float*)d_in[7];
    const float* elu  = (const float*)d_in[8];
    const float* elub = (const float*)d_in[9];
    const float* dWih = (const float*)d_in[10];
    const float* dWhh = (const float*)d_in[11];
    const float* dbih = (const float*)d_in[12];
    const float* dbhh = (const float*)d_in[13];
    const float* dlv  = (const float*)d_in[14];
    const float* dlw  = (const float*)d_in[15];
    const float* dlwb = (const float*)d_in[16];
    const float* dlu  = (const float*)d_in[17];
    const float* dlub = (const float*)d_in[18];
    const float* dlp  = (const float*)d_in[19];
    const float* dlpb = (const float*)d_in[20];
    const float* dly  = (const float*)d_in[21];
    const float* dlyb = (const float*)d_in[22];
    const int*   tgt  = (const int*)d_in[23];
    float* out = (float*)d_out;

    const size_t need = (size_t)NB * WW * 32 * sizeof(h2t);  // 16 MiB
    if (d_ws && ws_size >= need) {
        darnn_kernel<true><<<NB, 256, 0, stream>>>(
            x, eWih, eWhh, ebih, ebhh, elv, elw, elwb, elu, elub,
            dWih, dWhh, dbih, dbhh, dlv, dlw, dlwb, dlu, dlub,
            dlp, dlpb, dly, dlyb, tgt, (h2t*)d_ws, out);
    } else {
        darnn_kernel<false><<<NB, 256, 0, stream>>>(
            x, eWih, eWhh, ebih, ebhh, elv, elw, elwb, elu, elub,
            dWih, dWhh, dbih, dbhh, dlv, dlw, dlwb, dlu, dlub,
            dlp, dlpb, dly, dlyb, tgt, (h2t*)nullptr, out);
    }
}

// Round 5
// 1714.319 us; speedup vs baseline: 2.2572x; 1.0587x over previous
//
#include <hip/hip_runtime.h>

#define NB 1024
#define NV 96
#define WW 128
#define EE 64
#define DD 64

typedef _Float16 h2t __attribute__((ext_vector_type(2)));
typedef float f2t __attribute__((ext_vector_type(2)));
typedef float f4t __attribute__((ext_vector_type(4)));

#define CLOG 2.885390081777927f   /* 2*log2(e) */
#define L2E  1.4426950408889634f  /* log2(e)   */

__device__ __forceinline__ float fdot2(h2t a, h2t b, float c) {
    return __builtin_amdgcn_fdot2(a, b, c, false);
}
__device__ __forceinline__ h2t pk2(float a, float b) {
    h2t r; r.x = (_Float16)a; r.y = (_Float16)b; return r;
}
__device__ __forceinline__ h2t bch(float f) { return __builtin_bit_cast(h2t, f); }
__device__ __forceinline__ float bcf(h2t p) { return __builtin_bit_cast(float, p); }
__device__ __forceinline__ float ex2(float x) { return __builtin_amdgcn_exp2f(x); }
__device__ __forceinline__ float rcp_(float x) { return __builtin_amdgcn_rcpf(x); }
__device__ __forceinline__ float sig_c(float x) { return rcp_(1.f + ex2(-x * L2E)); }
__device__ __forceinline__ float tanh_c(float x) { return 1.f - 2.f * rcp_(ex2(x * CLOG) + 1.f); }
__device__ __forceinline__ float wsum(float v) {
#pragma unroll
    for (int o = 32; o; o >>= 1) v += __shfl_xor(v, o, 64);
    return v;
}

#define DOT4(V, WR, B, ACC) do { \
    ACC = fdot2(bch((V).x), (WR)[(B) + 0], ACC); \
    ACC = fdot2(bch((V).y), (WR)[(B) + 1], ACC); \
    ACC = fdot2(bch((V).z), (WR)[(B) + 2], ACC); \
    ACC = fdot2(bch((V).w), (WR)[(B) + 3], ACC); } while (0)

#define DOT4W(V, W4, ACC) do { \
    ACC = fdot2(bch((V).x), bch((W4).x), ACC); \
    ACC = fdot2(bch((V).y), bch((W4).y), ACC); \
    ACC = fdot2(bch((V).z), bch((W4).z), ACC); \
    ACC = fdot2(bch((V).w), bch((W4).w), ACC); } while (0)

// ======================= 2-elements-per-block kernel =======================
// grid = NB/2 = 512 blocks -> exactly 2 blocks/CU, ALL resident, one round.
// VGPR contract: (256,2) empirically caps allocation at 128 (r1/r4 evidence).
__global__ __launch_bounds__(256, 2)
void darnn2_kernel(
    const float* __restrict__ x,
    const float* __restrict__ eWih, const float* __restrict__ eWhh,
    const float* __restrict__ ebih, const float* __restrict__ ebhh,
    const float* __restrict__ elv,  const float* __restrict__ elw,
    const float* __restrict__ elwb, const float* __restrict__ elu,
    const float* __restrict__ elub,
    const float* __restrict__ dWih, const float* __restrict__ dWhh,
    const float* __restrict__ dbih, const float* __restrict__ dbhh,
    const float* __restrict__ dlv,  const float* __restrict__ dlw,
    const float* __restrict__ dlwb, const float* __restrict__ dlu,
    const float* __restrict__ dlub, const float* __restrict__ dlp,
    const float* __restrict__ dlpb, const float* __restrict__ dly,
    const float* __restrict__ dlyb, const int* __restrict__ tgtp,
    h2t* __restrict__ hsg_all,
    float* __restrict__ out)
{
    // u_e: h2t[96][64 k][2 el] (scaled by CLOG, k XOR-swizzled) | later u_d: [128][32][2]
    __shared__ __align__(16) h2t  s_ue[96 * 128];        // 49152 B
    __shared__ __align__(16) f4t  s_wo4[64];             // 1024 B {woA0,woA1,woB0,woB1}
    __shared__ __align__(16) f2t  s_lv[64];              // 512 B lv pairs (dec: dlv in [0..31])
    __shared__ __align__(16) f2t  s_soft2[128];          // 1024 B {eA,eB}
    __shared__ __align__(16) char s_u2v[2048];           // enc: xtA/xtB | dec: tmp4 f4[128]
    __shared__ __align__(16) h2t  s_hch2[2][2][64];      // 1024 B [pp][el][h|c pairs]
    __shared__ __align__(16) f4t  s_spw[4][256];         // 16384 B eWih pairs 32..47
    __shared__ __align__(16) f4t  s_sph[2][256];         // 8192 B  eWhh (dec: dWhh) pairs 24..31
    __shared__ float s_scal[8];

    h2t*  const s_xtA  = (h2t*)s_u2v;
    h2t*  const s_xtB  = (h2t*)(s_u2v + 1024);
    f4t*  const s_tmp4 = (f4t*)s_u2v;

    const int tid  = threadIdx.x;
    const int b    = blockIdx.x;
    const int lane = tid & 63, wq = tid >> 6;
    const int uidx = wq * 16 + (lane >> 2);
    const int jrow = (lane & 3) * 64 + uidx;
    const float* xbA = x + (size_t)(2 * b) * NV * WW;
    const float* xbB = xbA + NV * WW;
    h2t* hsgP = hsg_all + (size_t)b * (WW * 64);   // [w][32 k][2 el]

    float c_regA = 0.f, c_regB = 0.f;

    // ---------------- init ----------------
    if (tid >= 96 && tid < 128) { f2t z = {0.f, 0.f}; s_soft2[tid] = z; }
    if (tid < 64) {
        s_hch2[0][0][tid] = pk2(0.f, 0.f);
        s_hch2[0][1][tid] = pk2(0.f, 0.f);
        f2t lv = { elv[2 * tid], elv[2 * tid + 1] };
        s_lv[tid] = lv;
    }

    // ---------------- phase A: u_e for both elements ----------------
    {
        const int o = tid >> 1, p = tid & 1;
        f4t lu4[16];
        const f4t* lur = (const f4t*)(elu + o * WW + p * 64);
#pragma unroll
        for (int i = 0; i < 16; ++i) lu4[i] = lur[i];
        const float lub_o = elub[o];
        for (int n = 0; n < NV; ++n) {
            const f4t* xrA = (const f4t*)(xbA + n * WW + p * 64);
            const f4t* xrB = (const f4t*)(xbB + n * WW + p * 64);
            float aA = 0.f, aB = 0.f;
#pragma unroll
            for (int i = 0; i < 16; ++i) {
                f4t vA = xrA[i], vB = xrB[i], l4 = lu4[i];
                aA = fmaf(vA.x, l4.x, aA); aA = fmaf(vA.y, l4.y, aA);
                aA = fmaf(vA.z, l4.z, aA); aA = fmaf(vA.w, l4.w, aA);
                aB = fmaf(vB.x, l4.x, aB); aB = fmaf(vB.y, l4.y, aB);
                aB = fmaf(vB.z, l4.z, aB); aB = fmaf(vB.w, l4.w, aB);
            }
            aA += __shfl_xor(aA, 1, 64);
            aB += __shfl_xor(aB, 1, 64);
            float valA = (aA + lub_o) * CLOG;
            float valB = (aB + lub_o) * CLOG;
            float vnA = __shfl_xor(valA, 2, 64);
            float vnB = __shfl_xor(valB, 2, 64);
            if (!(tid & 3)) {
                const int k = tid >> 2;
                f2t st = { bcf(pk2(valA, vnA)), bcf(pk2(valB, vnB)) };
                *(f2t*)&s_ue[n * 128 + ((k ^ (n & 31)) << 1)] = st;
            }
        }
    }
    __syncthreads();
    __builtin_amdgcn_sched_barrier(0);

    float elvsum;
    { f2t lv = s_lv[lane]; elvsum = wsum(lv.x + lv.y); }

    // ---------------- encoder weights ----------------
    h2t lw_r[32];
    {
        const f2t* r = (const f2t*)(elw + (tid >> 1) * 128 + (tid & 1) * 64);
#pragma unroll
        for (int i = 0; i < 32; ++i) { f2t v = r[i]; lw_r[i] = pk2(v.x, v.y); }
    }
    const float lwb_r = elwb[tid >> 1];
    h2t wih_r[32];
    {
        const f2t* r = (const f2t*)(eWih + jrow * 96);
#pragma unroll
        for (int i = 0; i < 32; ++i) { f2t v = r[i]; wih_r[i] = pk2(v.x, v.y); }
#pragma unroll
        for (int g = 0; g < 4; ++g) {
            f4t ws;
            { f2t v = r[32 + 4*g];     ws.x = bcf(pk2(v.x, v.y)); }
            { f2t v = r[33 + 4*g];     ws.y = bcf(pk2(v.x, v.y)); }
            { f2t v = r[34 + 4*g];     ws.z = bcf(pk2(v.x, v.y)); }
            { f2t v = r[35 + 4*g];     ws.w = bcf(pk2(v.x, v.y)); }
            s_spw[g][tid] = ws;
        }
    }
    h2t whh_r[24];
    {
        const f2t* r = (const f2t*)(eWhh + jrow * 64);
#pragma unroll
        for (int i = 0; i < 24; ++i) { f2t v = r[i]; whh_r[i] = pk2(v.x, v.y); }
#pragma unroll
        for (int g = 0; g < 2; ++g) {
            f4t ws;
            { f2t v = r[24 + 4*g];     ws.x = bcf(pk2(v.x, v.y)); }
            { f2t v = r[25 + 4*g];     ws.y = bcf(pk2(v.x, v.y)); }
            { f2t v = r[26 + 4*g];     ws.z = bcf(pk2(v.x, v.y)); }
            { f2t v = r[27 + 4*g];     ws.w = bcf(pk2(v.x, v.y)); }
            s_sph[g][tid] = ws;
        }
    }
    const float bsum_r = ebih[jrow] + ebhh[jrow];
    __builtin_amdgcn_sched_barrier(0);

    // ---------------- encoder recurrence ----------------
#pragma unroll 1
    for (int t = 0; t < WW; ++t) {
        const int pp = t & 1;
        float xvA = 0.f, xvB = 0.f;
        if (!(tid & 1) && tid < 192) {
            const int n = tid >> 1;
            xvA = xbA[n * WW + t]; xvB = xbB[n * WW + t];
        }
        // ph1: w_out both elements
        {
            const f4t* hcA = (const f4t*)&s_hch2[pp][0][(tid & 1) * 32];
            const f4t* hcB = (const f4t*)&s_hch2[pp][1][(tid & 1) * 32];
            float aA = 0.f, aB = 0.f;
#pragma unroll
            for (int i = 0; i < 8; ++i) {
                f4t vA = hcA[i], vB = hcB[i];
                DOT4(vA, lw_r, 4 * i, aA);
                DOT4(vB, lw_r, 4 * i, aB);
            }
            aA += __shfl_xor(aA, 1, 64); aB += __shfl_xor(aB, 1, 64);
            float woA = (aA + lwb_r) * CLOG, woB = (aB + lwb_r) * CLOG;
            float wnA = __shfl_xor(woA, 2, 64), wnB = __shfl_xor(woB, 2, 64);
            if (!(tid & 3)) { f4t st = {woA, wnA, woB, wnB}; s_wo4[tid >> 2] = st; }
        }
        __syncthreads();
        // ph2: scores + exp, both elements
        float prodA = 0.f, prodB = 0.f;
        if (tid < 192) {
            const int n = tid >> 1, part = tid & 1, sw = n & 31;
            const h2t* uer = s_ue + n * 128;
            float aA = 0.f, aB = 0.f;
#pragma unroll
            for (int j = 0; j < 32; ++j) {
                const int wp = part * 32 + j;
                f4t w4 = s_wo4[wp];
                f2t lv = s_lv[wp];
                f2t up = *(const f2t*)&uer[(wp ^ sw) << 1];
                h2t uA = bch(up.x), uB = bch(up.y);
                float r0A = rcp_(ex2(w4.x + (float)uA.x) + 1.f);
                float r1A = rcp_(ex2(w4.y + (float)uA.y) + 1.f);
                float r0B = rcp_(ex2(w4.z + (float)uB.x) + 1.f);
                float r1B = rcp_(ex2(w4.w + (float)uB.y) + 1.f);
                aA = fmaf(lv.x, r0A, aA); aA = fmaf(lv.y, r1A, aA);
                aB = fmaf(lv.x, r0B, aB); aB = fmaf(lv.y, r1B, aB);
            }
            aA += __shfl_xor(aA, 1, 64); aB += __shfl_xor(aB, 1, 64);
            if (!(tid & 1)) {
                float eA = ex2((elvsum - 2.f * aA) * L2E);
                float eB = ex2((elvsum - 2.f * aB) * L2E);
                prodA = eA * xvA; prodB = eB * xvB;
                f2t st = {eA, eB}; s_soft2[tid >> 1] = st;
            }
        }
        __syncthreads();
        // ph3: normalize + x_tilde
        if (tid < 192) {
            const int l = tid & 63;
            f2t s0 = s_soft2[l], s1 = s_soft2[64 + l];
            float smA = s0.x + s1.x, smB = s0.y + s1.y;
#pragma unroll
            for (int o = 32; o; o >>= 1) {
                smA += __shfl_xor(smA, o, 64);
                smB += __shfl_xor(smB, o, 64);
            }
            float invA = rcp_(smA), invB = rcp_(smB);
            float p1A = __shfl_xor(prodA, 2, 64), p1B = __shfl_xor(prodB, 2, 64);
            if (!(tid & 3)) {
                s_xtA[tid >> 2] = pk2(prodA * invA, p1A * invA);
                s_xtB[tid >> 2] = pk2(prodB * invB, p1B * invB);
            }
        }
        __syncthreads();
        // ph4: gates + fused LSTM update, both elements
        {
            float gA = bsum_r, gB = bsum_r;
            const f4t* xtA4 = (const f4t*)s_xtA;
            const f4t* xtB4 = (const f4t*)s_xtB;
#pragma unroll
            for (int i = 0; i < 8; ++i) {
                f4t vA = xtA4[i], vB = xtB4[i];
                DOT4(vA, wih_r, 4 * i, gA);
                DOT4(vB, wih_r, 4 * i, gB);
            }
#pragma unroll
            for (int g = 0; g < 4; ++g) {
                f4t w = s_spw[g][tid];
                f4t vA = xtA4[8 + g], vB = xtB4[8 + g];
                DOT4W(vA, w, gA); DOT4W(vB, w, gB);
            }
            const f4t* hA4 = (const f4t*)&s_hch2[pp][0][0];
            const f4t* hB4 = (const f4t*)&s_hch2[pp][1][0];
#pragma unroll
            for (int i = 0; i < 6; ++i) {
                f4t vA = hA4[i], vB = hB4[i];
                DOT4(vA, whh_r, 4 * i, gA);
                DOT4(vB, whh_r, 4 * i, gB);
            }
#pragma unroll
            for (int g = 0; g < 2; ++g) {
                f4t w = s_sph[g][tid];
                f4t vA = hA4[6 + g], vB = hB4[6 + g];
                DOT4W(vA, w, gA); DOT4W(vB, w, gB);
            }
            const int base = lane & ~3;
            float giA = __shfl(gA, base, 64),     giB = __shfl(gB, base, 64);
            float gfA = __shfl(gA, base + 1, 64), gfB = __shfl(gB, base + 1, 64);
            float g2A = __shfl(gA, base + 2, 64), g2B = __shfl(gB, base + 2, 64);
            float goA = __shfl(gA, base + 3, 64), goB = __shfl(gB, base + 3, 64);
            float cA = sig_c(gfA) * c_regA + sig_c(giA) * tanh_c(g2A);
            float cB = sig_c(gfB) * c_regB + sig_c(giB) * tanh_c(g2B);
            float hA = sig_c(goA) * tanh_c(cA);
            float hB = sig_c(goB) * tanh_c(cB);
            c_regA = cA; c_regB = cB;
            float hnA = __shfl_xor(hA, 4, 64), cnA = __shfl_xor(cA, 4, 64);
            float hnB = __shfl_xor(hB, 4, 64), cnB = __shfl_xor(cB, 4, 64);
            if (!(lane & 7)) {
                const int k = wq * 8 + (lane >> 3);
                h2t phA = pk2(hA, hnA), phB = pk2(hB, hnB);
                s_hch2[pp ^ 1][0][k]      = phA;
                s_hch2[pp ^ 1][0][32 + k] = pk2(cA, cnA);
                s_hch2[pp ^ 1][1][k]      = phB;
                s_hch2[pp ^ 1][1][32 + k] = pk2(cB, cnB);
                f2t st = { bcf(phA), bcf(phB) };
                *(f2t*)&hsgP[t * 64 + k * 2] = st;
            }
        }
        __syncthreads();
    }

    // ---------------- u_d = h_seq @ dlu^T + dlub, both elements ----------------
    {
        const int e2h = tid & 31;
        h2t du0[32], du1[32];
        {
            const f4t* p0 = (const f4t*)(dlu + (2 * e2h) * 64);
            const f4t* p1 = (const f4t*)(dlu + (2 * e2h + 1) * 64);
#pragma unroll
            for (int i = 0; i < 16; ++i) {
                f4t v0 = p0[i], v1 = p1[i];
                du0[2 * i] = pk2(v0.x, v0.y); du0[2 * i + 1] = pk2(v0.z, v0.w);
                du1[2 * i] = pk2(v1.x, v1.y); du1[2 * i + 1] = pk2(v1.z, v1.w);
            }
        }
        const float b0 = dlub[2 * e2h], b1 = dlub[2 * e2h + 1];
#pragma unroll 1
        for (int pass = 0; pass < 16; ++pass) {
            const int w = pass * 8 + (tid >> 5);
            float a0A = b0, a1A = b1, a0B = b0, a1B = b1;
            const f4t* hr = (const f4t*)(hsgP + w * 64);
#pragma unroll
            for (int i = 0; i < 16; ++i) {
                f4t v = hr[i];
                a0A = fdot2(bch(v.x), du0[2*i], a0A); a0A = fdot2(bch(v.z), du0[2*i+1], a0A);
                a1A = fdot2(bch(v.x), du1[2*i], a1A); a1A = fdot2(bch(v.z), du1[2*i+1], a1A);
                a0B = fdot2(bch(v.y), du0[2*i], a0B); a0B = fdot2(bch(v.w), du0[2*i+1], a0B);
                a1B = fdot2(bch(v.y), du1[2*i], a1B); a1B = fdot2(bch(v.w), du1[2*i+1], a1B);
            }
            f2t st = { bcf(pk2(a0A * CLOG, a1A * CLOG)), bcf(pk2(a0B * CLOG, a1B * CLOG)) };
            *(f2t*)&s_ue[w * 64 + ((e2h ^ (w & 31)) << 1)] = st;
        }
    }
    __builtin_amdgcn_sched_barrier(0);

    // ---------------- decoder setup ----------------
    const int tgt = tgtp[0];
    if (tid < 32) { f2t lv = { dlv[2 * tid], dlv[2 * tid + 1] }; s_lv[tid] = lv; }
    if (tid < 64) {
        s_hch2[0][0][tid] = pk2(0.f, 0.f);
        s_hch2[0][1][tid] = pk2(0.f, 0.f);
    }
    float dlvsum;
    { float v = dlv[lane]; dlvsum = wsum(v); }
    h2t dlw_r[16];
    {
        const f2t* r = (const f2t*)(dlw + (tid >> 2) * 128 + (tid & 3) * 32);
#pragma unroll
        for (int i = 0; i < 16; ++i) { f2t v = r[i]; dlw_r[i] = pk2(v.x, v.y); }
    }
    const float dlwb_r = dlwb[tid >> 2];
    h2t dwhh_r[24];
    {
        const f2t* r = (const f2t*)(dWhh + jrow * 64);
#pragma unroll
        for (int i = 0; i < 24; ++i) { f2t v = r[i]; dwhh_r[i] = pk2(v.x, v.y); }
#pragma unroll
        for (int g = 0; g < 2; ++g) {
            f4t ws;
            { f2t v = r[24 + 4*g]; ws.x = bcf(pk2(v.x, v.y)); }
            { f2t v = r[25 + 4*g]; ws.y = bcf(pk2(v.x, v.y)); }
            { f2t v = r[26 + 4*g]; ws.z = bcf(pk2(v.x, v.y)); }
            { f2t v = r[27 + 4*g]; ws.w = bcf(pk2(v.x, v.y)); }
            s_sph[g][tid] = ws;
        }
    }
    const float dwih_r  = dWih[jrow];
    const float dbsum_r = dbih[jrow] + dbhh[jrow];
    const float lp0     = dlp[0];
    const float lp1_r   = dlp[1 + lane];
    const float lpb     = dlpb[0];
    c_regA = 0.f; c_regB = 0.f;
    float h_regA = 0.f, h_regB = 0.f;
    __syncthreads();

    // ---------------- decoder recurrence ----------------
#pragma unroll 1
    for (int s = 0; s < WW - 1; ++s) {
        const int pp = s & 1;
        const float ysA = xbA[(size_t)tgt * WW + s];
        const float ysB = xbB[(size_t)tgt * WW + s];
        // ph1': w_out_d both elements
        {
            const f4t* hcA = (const f4t*)&s_hch2[pp][0][(tid & 3) * 16];
            const f4t* hcB = (const f4t*)&s_hch2[pp][1][(tid & 3) * 16];
            float aA = 0.f, aB = 0.f;
#pragma unroll
            for (int i = 0; i < 4; ++i) {
                f4t vA = hcA[i], vB = hcB[i];
                DOT4(vA, dlw_r, 4 * i, aA);
                DOT4(vB, dlw_r, 4 * i, aB);
            }
            aA += __shfl_xor(aA, 1, 64); aB += __shfl_xor(aB, 1, 64);
            aA += __shfl_xor(aA, 2, 64); aB += __shfl_xor(aB, 2, 64);
            float woA = (aA + dlwb_r) * CLOG, woB = (aB + dlwb_r) * CLOG;
            float wnA = __shfl_xor(woA, 4, 64), wnB = __shfl_xor(woB, 4, 64);
            if (!(tid & 7)) { f4t st = {woA, wnA, woB, wnB}; s_wo4[tid >> 3] = st; }
        }
        __syncthreads();
        // ph2': v scores + exp
        {
            const int w = tid >> 1, part = tid & 1, sw = w & 31;
            const h2t* udr = s_ue + w * 64;
            float aA = 0.f, aB = 0.f;
#pragma unroll
            for (int j = 0; j < 16; ++j) {
                const int ep = part * 16 + j;
                f4t w4 = s_wo4[ep];
                f2t lv = s_lv[ep];
                f2t up = *(const f2t*)&udr[(ep ^ sw) << 1];
                h2t uA = bch(up.x), uB = bch(up.y);
                float r0A = rcp_(ex2(w4.x + (float)uA.x) + 1.f);
                float r1A = rcp_(ex2(w4.y + (float)uA.y) + 1.f);
                float r0B = rcp_(ex2(w4.z + (float)uB.x) + 1.f);
                float r1B = rcp_(ex2(w4.w + (float)uB.y) + 1.f);
                aA = fmaf(lv.x, r0A, aA); aA = fmaf(lv.y, r1A, aA);
                aB = fmaf(lv.x, r0B, aB); aB = fmaf(lv.y, r1B, aB);
            }
            aA += __shfl_xor(aA, 1, 64); aB += __shfl_xor(aB, 1, 64);
            if (!(tid & 1)) {
                float eA = ex2((dlvsum - 2.f * aA) * L2E);
                float eB = ex2((dlvsum - 2.f * aB) * L2E);
                f2t st = {eA, eB}; s_soft2[w] = st;
            }
        }
        __syncthreads();
        // ph3': softmax sums + context partials
        float invA, invB;
        {
            const int l = tid & 63;
            f2t s0 = s_soft2[l], s1 = s_soft2[64 + l];
            float smA = s0.x + s1.x, smB = s0.y + s1.y;
#pragma unroll
            for (int o = 32; o; o >>= 1) {
                smA += __shfl_xor(smA, o, 64);
                smB += __shfl_xor(smB, o, 64);
            }
            invA = rcp_(smA); invB = rcp_(smB);
            const int e2 = tid & 31, pg = tid >> 5;
            float a0A = 0.f, a1A = 0.f, a0B = 0.f, a1B = 0.f;
#pragma unroll
            for (int j = 0; j < 16; ++j) {
                const int w = pg * 16 + j;
                f2t be = s_soft2[w];
                f2t hp = *(const f2t*)&hsgP[w * 64 + e2 * 2];
                h2t hA = bch(hp.x), hB = bch(hp.y);
                a0A = fmaf(be.x, (float)hA.x, a0A); a1A = fmaf(be.x, (float)hA.y, a1A);
                a0B = fmaf(be.y, (float)hB.x, a0B); a1B = fmaf(be.y, (float)hB.y, a1B);
            }
            a0A += __shfl_xor(a0A, 32, 64); a1A += __shfl_xor(a1A, 32, 64);
            a0B += __shfl_xor(a0B, 32, 64); a1B += __shfl_xor(a1B, 32, 64);
            if ((tid & 63) < 32) { f4t st = {a0A, a1A, a0B, a1B}; s_tmp4[wq * 32 + e2] = st; }
        }
        __syncthreads();
        // ph4': y_tilde + gates + update
        {
            const int l = tid & 63;
            const int eh = l >> 1;
            f4t p0 = s_tmp4[eh], p1 = s_tmp4[32 + eh], p2 = s_tmp4[64 + eh], p3 = s_tmp4[96 + eh];
            float ctxA = (l & 1) ? (p0.y + p1.y + p2.y + p3.y) : (p0.x + p1.x + p2.x + p3.x);
            float ctxB = (l & 1) ? (p0.w + p1.w + p2.w + p3.w) : (p0.z + p1.z + p2.z + p3.z);
            float termA = ctxA * invA * lp1_r;
            float termB = ctxB * invB * lp1_r;
#pragma unroll
            for (int o = 32; o; o >>= 1) {
                termA += __shfl_xor(termA, o, 64);
                termB += __shfl_xor(termB, o, 64);
            }
            float ytA = fmaf(ysA, lp0, termA + lpb);
            float ytB = fmaf(ysB, lp0, termB + lpb);
            float gA = fmaf(ytA, dwih_r, dbsum_r);
            float gB = fmaf(ytB, dwih_r, dbsum_r);
            const f4t* hA4 = (const f4t*)&s_hch2[pp][0][0];
            const f4t* hB4 = (const f4t*)&s_hch2[pp][1][0];
#pragma unroll
            for (int i = 0; i < 6; ++i) {
                f4t vA = hA4[i], vB = hB4[i];
                DOT4(vA, dwhh_r, 4 * i, gA);
                DOT4(vB, dwhh_r, 4 * i, gB);
            }
#pragma unroll
            for (int g = 0; g < 2; ++g) {
                f4t w = s_sph[g][tid];
                f4t vA = hA4[6 + g], vB = hB4[6 + g];
                DOT4W(vA, w, gA); DOT4W(vB, w, gB);
            }
            const int base = lane & ~3;
            float giA = __shfl(gA, base, 64),     giB = __shfl(gB, base, 64);
            float gfA = __shfl(gA, base + 1, 64), gfB = __shfl(gB, base + 1, 64);
            float g2A = __shfl(gA, base + 2, 64), g2B = __shfl(gB, base + 2, 64);
            float goA = __shfl(gA, base + 3, 64), goB = __shfl(gB, base + 3, 64);
            float cA = sig_c(gfA) * c_regA + sig_c(giA) * tanh_c(g2A);
            float cB = sig_c(gfB) * c_regB + sig_c(giB) * tanh_c(g2B);
            float hA = sig_c(goA) * tanh_c(cA);
            float hB = sig_c(goB) * tanh_c(cB);
            c_regA = cA; c_regB = cB; h_regA = hA; h_regB = hB;
            float hnA = __shfl_xor(hA, 4, 64), cnA = __shfl_xor(cA, 4, 64);
            float hnB = __shfl_xor(hB, 4, 64), cnB = __shfl_xor(cB, 4, 64);
            if (!(lane & 7)) {
                const int k = wq * 8 + (lane >> 3);
                s_hch2[pp ^ 1][0][k]      = pk2(hA, hnA);
                s_hch2[pp ^ 1][0][32 + k] = pk2(cA, cnA);
                s_hch2[pp ^ 1][1][k]      = pk2(hB, hnB);
                s_hch2[pp ^ 1][1][32 + k] = pk2(cB, cnB);
            }
        }
        __syncthreads();
    }

    // ---------------- output ----------------
    {
        float termA = 0.f, termB = 0.f;
        if (!(lane & 3)) {
            termA = h_regA * dly[uidx] + c_regA * dly[64 + uidx];
            termB = h_regB * dly[uidx] + c_regB * dly[64 + uidx];
        }
#pragma unroll
        for (int o = 32; o; o >>= 1) {
            termA += __shfl_xor(termA, o, 64);
            termB += __shfl_xor(termB, o, 64);
        }
        if (lane == 0) { s_scal[wq] = termA; s_scal[4 + wq] = termB; }
    }
    __syncthreads();
    if (tid == 0) out[2 * b]     = s_scal[0] + s_scal[1] + s_scal[2] + s_scal[3] + dlyb[0];
    if (tid == 1) out[2 * b + 1] = s_scal[4] + s_scal[5] + s_scal[6] + s_scal[7] + dlyb[0];
}

// ======================= fallback: r4 1-element kernel (LDS h_seq) ========
__global__ __launch_bounds__(256, 2)
void darnn1_kernel(
    const float* __restrict__ x,
    const float* __restrict__ eWih, const float* __restrict__ eWhh,
    const float* __restrict__ ebih, const float* __restrict__ ebhh,
    const float* __restrict__ elv,  const float* __restrict__ elw,
    const float* __restrict__ elwb, const float* __restrict__ elu,
    const float* __restrict__ elub,
    const float* __restrict__ dWih, const float* __restrict__ dWhh,
    const float* __restrict__ dbih, const float* __restrict__ dbhh,
    const float* __restrict__ dlv,  const float* __restrict__ dlw,
    const float* __restrict__ dlwb, const float* __restrict__ dlu,
    const float* __restrict__ dlub, const float* __restrict__ dlp,
    const float* __restrict__ dlpb, const float* __restrict__ dly,
    const float* __restrict__ dlyb, const int* __restrict__ tgtp,
    float* __restrict__ out)
{
    __shared__ __align__(16) h2t  s_pool[96 * 64];
    __shared__ __align__(16) h2t  s_hseq2[WW][32];
    __shared__ __align__(16) f4t  s_wlv[64];
    __shared__ __align__(16) char s_u2[1024];
    __shared__ __align__(16) float s_soft[128];
    __shared__ __align__(16) h2t  s_hch2[2][64];
    __shared__ __align__(16) f4t  s_spillh[2][256];
    __shared__ __align__(16) f4t  s_spillw[256];

    float* s_wlvf = (float*)s_wlv;
    h2t*  const s_xt  = (h2t*)s_u2;
    float* const s_tmp = (float*)s_u2;

    const int tid  = threadIdx.x;
    const int b    = blockIdx.x;
    const int lane = tid & 63, wq = tid >> 6;
    const int uidx = wq * 16 + (lane >> 2);
    const int jrow = (lane & 3) * 64 + uidx;
    const float* xb = x + (size_t)b * NV * WW;

    float c_reg = 0.f;

    if (tid >= 96 && tid < 128) s_soft[tid] = 0.f;
    if (tid < 64) {
        s_hch2[0][tid] = pk2(0.f, 0.f);
        s_wlvf[tid * 4 + 2] = elv[2 * tid];
        s_wlvf[tid * 4 + 3] = elv[2 * tid + 1];
    }
    {
        const int o = tid >> 1, p = tid & 1;
        f4t lu4[16];
        const f4t* lur = (const f4t*)(elu + o * WW + p * 64);
#pragma unroll
        for (int i = 0; i < 16; ++i) lu4[i] = lur[i];
        const float lub_o = elub[o];
        for (int n = 0; n < NV; ++n) {
            const f4t* xr = (const f4t*)(xb + n * WW + p * 64);
            float a = 0.f;
#pragma unroll
            for (int i = 0; i < 16; ++i) {
                f4t v = xr[i], l4 = lu4[i];
                a = fmaf(v.x, l4.x, a); a = fmaf(v.y, l4.y, a);
                a = fmaf(v.z, l4.z, a); a = fmaf(v.w, l4.w, a);
            }
            a += __shfl_xor(a, 1, 64);
            float val = (a + lub_o) * CLOG;
            float vn  = __shfl_xor(val, 2, 64);
            if (!(tid & 3)) s_pool[n * 64 + ((tid >> 2) ^ (n & 31))] = pk2(val, vn);
        }
    }
    __syncthreads();
    __builtin_amdgcn_sched_barrier(0);

    float elvsum;
    {
        const f2t lvp = *(const f2t*)&s_wlvf[(tid & 63) * 4 + 2];
        elvsum = wsum(lvp.x + lvp.y);
    }
    h2t lw_r[32];
    {
        const f2t* r = (const f2t*)(elw + (tid >> 1) * 128 + (tid & 1) * 64);
#pragma unroll
        for (int i = 0; i < 32; ++i) { f2t v = r[i]; lw_r[i] = pk2(v.x, v.y); }
    }
    const float lwb_r = elwb[tid >> 1];
    h2t wih_r[44];
    {
        const f2t* r = (const f2t*)(eWih + jrow * 96);
#pragma unroll
        for (int i = 0; i < 44; ++i) { f2t v = r[i]; wih_r[i] = pk2(v.x, v.y); }
        f4t ws;
        { f2t v = r[44]; ws.x = bcf(pk2(v.x, v.y)); }
        { f2t v = r[45]; ws.y = bcf(pk2(v.x, v.y)); }
        { f2t v = r[46]; ws.z = bcf(pk2(v.x, v.y)); }
        { f2t v = r[47]; ws.w = bcf(pk2(v.x, v.y)); }
        s_spillw[tid] = ws;
    }
    h2t whh_r[24];
    {
        const f2t* r = (const f2t*)(eWhh + jrow * 64);
#pragma unroll
        for (int i = 0; i < 24; ++i) { f2t v = r[i]; whh_r[i] = pk2(v.x, v.y); }
        f4t w0, w1;
        { f2t v = r[24]; w0.x = bcf(pk2(v.x, v.y)); }
        { f2t v = r[25]; w0.y = bcf(pk2(v.x, v.y)); }
        { f2t v = r[26]; w0.z = bcf(pk2(v.x, v.y)); }
        { f2t v = r[27]; w0.w = bcf(pk2(v.x, v.y)); }
        { f2t v = r[28]; w1.x = bcf(pk2(v.x, v.y)); }
        { f2t v = r[29]; w1.y = bcf(pk2(v.x, v.y)); }
        { f2t v = r[30]; w1.z = bcf(pk2(v.x, v.y)); }
        { f2t v = r[31]; w1.w = bcf(pk2(v.x, v.y)); }
        s_spillh[0][tid] = w0;
        s_spillh[1][tid] = w1;
    }
    const float bsum_r = ebih[jrow] + ebhh[jrow];
    __builtin_amdgcn_sched_barrier(0);

#pragma unroll 1
    for (int t = 0; t < WW; ++t) {
        const int pp = t & 1;
        float xv = 0.f;
        if (!(tid & 1) && tid < 192) xv = xb[(tid >> 1) * WW + t];
        {
            const f4t* hc4 = (const f4t*)&s_hch2[pp][(tid & 1) * 32];
            float a = 0.f;
#pragma unroll
            for (int i = 0; i < 8; ++i) { f4t v = hc4[i]; DOT4(v, lw_r, 4 * i, a); }
            a += __shfl_xor(a, 1, 64);
            float wo = (a + lwb_r) * CLOG;
            float wn = __shfl_xor(wo, 2, 64);
            if (!(tid & 3)) { f2t st = {wo, wn}; *(f2t*)&s_wlvf[(tid >> 2) * 4] = st; }
        }
        __syncthreads();
        float prod = 0.f;
        if (tid < 192) {
            const int n = tid >> 1, sw = n & 31;
            const h2t* uer = s_pool + n * 64;
            float a = 0.f;
#pragma unroll
            for (int j = 0; j < 32; ++j) {
                const int wp = (tid & 1) * 32 + j;
                f4t wl = s_wlv[wp];
                h2t u  = uer[wp ^ sw];
                float r0 = rcp_(ex2(wl.x + (float)u.x) + 1.f);
                float r1 = rcp_(ex2(wl.y + (float)u.y) + 1.f);
                a = fmaf(wl.z, r0, a);
                a = fmaf(wl.w, r1, a);
            }
            a += __shfl_xor(a, 1, 64);
            if (!(tid & 1)) {
                float e = ex2((elvsum - 2.f * a) * L2E);
                prod = e * xv;
                s_soft[tid >> 1] = e;
            }
        }
        __syncthreads();
        if (tid < 192) {
            const int l = tid & 63;
            float sm = s_soft[l] + s_soft[64 + l];
            sm = wsum(sm);
            float inv = rcp_(sm);
            float p1 = __shfl_xor(prod, 2, 64);
            if (!(tid & 3)) s_xt[tid >> 2] = pk2(prod * inv, p1 * inv);
        }
        __syncthreads();
        {
            float gv = bsum_r;
            const f4t* xt4 = (const f4t*)s_xt;
#pragma unroll
            for (int i = 0; i < 11; ++i) { f4t v = xt4[i]; DOT4(v, wih_r, 4 * i, gv); }
            { f4t v = xt4[11]; f4t w = s_spillw[tid]; DOT4W(v, w, gv); }
            const f4t* h4 = (const f4t*)&s_hch2[pp][0];
#pragma unroll
            for (int i = 0; i < 6; ++i) { f4t v = h4[i]; DOT4(v, whh_r, 4 * i, gv); }
            { f4t v = h4[6]; f4t w = s_spillh[0][tid]; DOT4W(v, w, gv); }
            { f4t v = h4[7]; f4t w = s_spillh[1][tid]; DOT4W(v, w, gv); }
            const int base = lane & ~3;
            float gi = __shfl(gv, base, 64);
            float gf = __shfl(gv, base + 1, 64);
            float g2 = __shfl(gv, base + 2, 64);
            float go = __shfl(gv, base + 3, 64);
            float c = sig_c(gf) * c_reg + sig_c(gi) * tanh_c(g2);
            float h = sig_c(go) * tanh_c(c);
            c_reg = c;
            float hn = __shfl_xor(h, 4, 64);
            float cn = __shfl_xor(c, 4, 64);
            if (!(lane & 7)) {
                const int k = wq * 8 + (lane >> 3);
                s_hch2[pp ^ 1][k]      = pk2(h, hn);
                s_hch2[pp ^ 1][32 + k] = pk2(c, cn);
                s_hseq2[t][k ^ (t & 31)] = pk2(h, hn);
            }
        }
        __syncthreads();
    }
    {
        const int e2h = tid & 31;
        h2t du0[32], du1[32];
        {
            const f4t* p0 = (const f4t*)(dlu + (2 * e2h) * 64);
            const f4t* p1 = (const f4t*)(dlu + (2 * e2h + 1) * 64);
#pragma unroll
            for (int i = 0; i < 16; ++i) {
                f4t v0 = p0[i], v1 = p1[i];
                du0[2 * i] = pk2(v0.x, v0.y); du0[2 * i + 1] = pk2(v0.z, v0.w);
                du1[2 * i] = pk2(v1.x, v1.y); du1[2 * i + 1] = pk2(v1.z, v1.w);
            }
        }
        const float b0 = dlub[2 * e2h], b1 = dlub[2 * e2h + 1];
#pragma unroll 1
        for (int pass = 0; pass < 16; ++pass) {
            const int w = pass * 8 + (tid >> 5);
            float a0 = b0, a1 = b1;
            const int sww = w & 31;
#pragma unroll
            for (int i = 0; i < 32; ++i) {
                h2t hp = s_hseq2[w][i ^ sww];
                a0 = fdot2(hp, du0[i], a0);
                a1 = fdot2(hp, du1[i], a1);
            }
            s_pool[w * 32 + (e2h ^ (w & 31))] = pk2(a0 * CLOG, a1 * CLOG);
        }
    }
    __builtin_amdgcn_sched_barrier(0);

    const int tgt = tgtp[0];
    if (tid < 32) {
        s_wlvf[tid * 4 + 2] = dlv[2 * tid];
        s_wlvf[tid * 4 + 3] = dlv[2 * tid + 1];
    }
    if (tid < 64) s_hch2[0][tid] = pk2(0.f, 0.f);
    float dlvsum;
    { float v = dlv[tid & 63]; dlvsum = wsum(v); }
    h2t dlw_r[16];
    {
        const f2t* r = (const f2t*)(dlw + (tid >> 2) * 128 + (tid & 3) * 32);
#pragma unroll
        for (int i = 0; i < 16; ++i) { f2t v = r[i]; dlw_r[i] = pk2(v.x, v.y); }
    }
    const float dlwb_r = dlwb[tid >> 2];
    h2t dwhh_r[32];
    {
        const f2t* r = (const f2t*)(dWhh + jrow * 64);
#pragma unroll
        for (int i = 0; i < 32; ++i) { f2t v = r[i]; dwhh_r[i] = pk2(v.x, v.y); }
    }
    const float dwih_r  = dWih[jrow];
    const float dbsum_r = dbih[jrow] + dbhh[jrow];
    const float lp0     = dlp[0];
    const float lp1_r   = dlp[1 + (tid & 63)];
    const float lpb     = dlpb[0];
    c_reg = 0.f;
    float h_reg = 0.f;
    __syncthreads();

#pragma unroll 1
    for (int s = 0; s < WW - 1; ++s) {
        const int pp = s & 1;
        const float ys = xb[(size_t)tgt * WW + s];
        {
            const f4t* hc4 = (const f4t*)&s_hch2[pp][(tid & 3) * 16];
            float a = 0.f;
#pragma unroll
            for (int i = 0; i < 4; ++i) { f4t v = hc4[i]; DOT4(v, dlw_r, 4 * i, a); }
            a += __shfl_xor(a, 1, 64);
            a += __shfl_xor(a, 2, 64);
            float wo = (a + dlwb_r) * CLOG;
            float wn = __shfl_xor(wo, 4, 64);
            if (!(tid & 7)) { f2t st = {wo, wn}; *(f2t*)&s_wlvf[(tid >> 3) * 4] = st; }
        }
        __syncthreads();
        {
            const int w = tid >> 1, sw = w & 31;
            const h2t* udr = s_pool + w * 32;
            float a = 0.f;
#pragma unroll
            for (int j = 0; j < 16; ++j) {
                const int ep = (tid & 1) * 16 + j;
                f4t wl = s_wlv[ep];
                h2t u  = udr[ep ^ sw];
                float r0 = rcp_(ex2(wl.x + (float)u.x) + 1.f);
                float r1 = rcp_(ex2(wl.y + (float)u.y) + 1.f);
                a = fmaf(wl.z, r0, a);
                a = fmaf(wl.w, r1, a);
            }
            a += __shfl_xor(a, 1, 64);
            if (!(tid & 1)) s_soft[w] = ex2((dlvsum - 2.f * a) * L2E);
        }
        __syncthreads();
        float inv;
        {
            const int l = tid & 63;
            float sm = s_soft[l] + s_soft[64 + l];
            sm = wsum(sm);
            inv = rcp_(sm);
            const int e2 = tid & 31, pg = tid >> 5;
            float a0 = 0.f, a1 = 0.f;
#pragma unroll
            for (int j = 0; j < 16; ++j) {
                const int w = pg * 16 + j;
                float bw = s_soft[w];
                h2t hp = s_hseq2[w][e2 ^ (w & 31)];
                a0 = fmaf(bw, (float)hp.x, a0);
                a1 = fmaf(bw, (float)hp.y, a1);
            }
            a0 += __shfl_xor(a0, 32, 64);
            a1 += __shfl_xor(a1, 32, 64);
            if ((tid & 63) < 32) { f2t st = {a0, a1}; *(f2t*)&s_tmp[wq * 64 + e2 * 2] = st; }
        }
        __syncthreads();
        {
            const int l = tid & 63;
            float ctx = s_tmp[l] + s_tmp[64 + l] + s_tmp[128 + l] + s_tmp[192 + l];
            float term = ctx * inv * lp1_r;
            term = wsum(term);
            float yt = fmaf(ys, lp0, term + lpb);
            float gv = fmaf(yt, dwih_r, dbsum_r);
            const f4t* h4 = (const f4t*)&s_hch2[pp][0];
#pragma unroll
            for (int i = 0; i < 8; ++i) { f4t v = h4[i]; DOT4(v, dwhh_r, 4 * i, gv); }
            const int base = lane & ~3;
            float gi = __shfl(gv, base, 64);
            float gf = __shfl(gv, base + 1, 64);
            float g2 = __shfl(gv, base + 2, 64);
            float go = __shfl(gv, base + 3, 64);
            float c = sig_c(gf) * c_reg + sig_c(gi) * tanh_c(g2);
            float h = sig_c(go) * tanh_c(c);
            c_reg = c; h_reg = h;
            float hn = __shfl_xor(h, 4, 64);
            float cn = __shfl_xor(c, 4, 64);
            if (!(lane & 7)) {
                const int k = wq * 8 + (lane >> 3);
                s_hch2[pp ^ 1][k]      = pk2(h, hn);
                s_hch2[pp ^ 1][32 + k] = pk2(c, cn);
            }
        }
        __syncthreads();
    }
    {
        float term = 0.f;
        if (!(lane & 3)) term = h_reg * dly[uidx] + c_reg * dly[64 + uidx];
        term = wsum(term);
        if (lane == 0) s_tmp[wq] = term;
    }
    __syncthreads();
    if (tid == 0) out[b] = s_tmp[0] + s_tmp[1] + s_tmp[2] + s_tmp[3] + dlyb[0];
}

extern "C" void kernel_launch(void* const* d_in, const int* in_sizes, int n_in,
                              void* d_out, int out_size, void* d_ws, size_t ws_size,
                              hipStream_t stream) {
    (void)in_sizes; (void)n_in; (void)out_size;
    const float* x    = (const float*)d_in[0];
    const float* eWih = (const float*)d_in[1];
    const float* eWhh = (const float*)d_in[2];
    const float* ebih = (const float*)d_in[3];
    const float* ebhh = (const float*)d_in[4];
    const float* elv  = (const float*)d_in[5];
    const float* elw  = (const float*)d_in[6];
    const float* elwb = (const float*)d_in[7];
    const float* elu  = (const float*)d_in[8];
    const float* elub = (const float*)d_in[9];
    const float* dWih = (const float*)d_in[10];
    const float* dWhh = (const float*)d_in[11];
    const float* dbih = (const float*)d_in[12];
    const float* dbhh = (const float*)d_in[13];
    const float* dlv  = (const float*)d_in[14];
    const float* dlw  = (const float*)d_in[15];
    const float* dlwb = (const float*)d_in[16];
    const float* dlu  = (const float*)d_in[17];
    const float* dlub = (const float*)d_in[18];
    const float* dlp  = (const float*)d_in[19];
    const float* dlpb = (const float*)d_in[20];
    const float* dly  = (const float*)d_in[21];
    const float* dlyb = (const float*)d_in[22];
    const int*   tgt  = (const int*)d_in[23];
    float* out = (float*)d_out;

    const size_t need = (size_t)NB * WW * 32 * sizeof(h2t);  // 16 MiB
    if (d_ws && ws_size >= need) {
        darnn2_kernel<<<NB / 2, 256, 0, stream>>>(
            x, eWih, eWhh, ebih, ebhh, elv, elw, elwb, elu, elub,
            dWih, dWhh, dbih, dbhh, dlv, dlw, dlwb, dlu, dlub,
            dlp, dlpb, dly, dlyb, tgt, (h2t*)d_ws, out);
    } else {
        darnn1_kernel<<<NB, 256, 0, stream>>>(
            x, eWih, eWhh, ebih, ebhh, elv, elw, elwb, elu, elub,
            dWih, dWhh, dbih, dbhh, dlv, dlw, dlwb, dlu, dlub,
            dlp, dlpb, dly, dlyb, tgt, out);
    }
}

// Round 6
// 1663.637 us; speedup vs baseline: 2.3260x; 1.0305x over previous
//
#include <hip/hip_runtime.h>

#define NB 1024
#define NV 96
#define WW 128
#define EE 64
#define DD 64

typedef _Float16 h2t __attribute__((ext_vector_type(2)));
typedef float f2t __attribute__((ext_vector_type(2)));
typedef float f4t __attribute__((ext_vector_type(4)));

#define CLOG 2.885390081777927f   /* 2*log2(e) */
#define L2E  1.4426950408889634f  /* log2(e)   */

__device__ __forceinline__ float fdot2(h2t a, h2t b, float c) {
    return __builtin_amdgcn_fdot2(a, b, c, false);
}
__device__ __forceinline__ h2t pk2(float a, float b) {
    h2t r; r.x = (_Float16)a; r.y = (_Float16)b; return r;
}
__device__ __forceinline__ h2t bch(float f) { return __builtin_bit_cast(h2t, f); }
__device__ __forceinline__ float bcf(h2t p) { return __builtin_bit_cast(float, p); }
__device__ __forceinline__ float ex2(float x) { return __builtin_amdgcn_exp2f(x); }
__device__ __forceinline__ float rcp_(float x) { return __builtin_amdgcn_rcpf(x); }
__device__ __forceinline__ float sig_c(float x) { return rcp_(1.f + ex2(-x * L2E)); }
__device__ __forceinline__ float tanh_c(float x) { return 1.f - 2.f * rcp_(ex2(x * CLOG) + 1.f); }
__device__ __forceinline__ float wsum(float v) {
#pragma unroll
    for (int o = 32; o; o >>= 1) v += __shfl_xor(v, o, 64);
    return v;
}

#define DOT4(V, WR, B, ACC) do { \
    ACC = fdot2(bch((V).x), (WR)[(B) + 0], ACC); \
    ACC = fdot2(bch((V).y), (WR)[(B) + 1], ACC); \
    ACC = fdot2(bch((V).z), (WR)[(B) + 2], ACC); \
    ACC = fdot2(bch((V).w), (WR)[(B) + 3], ACC); } while (0)

#define DOT4W(V, W4, ACC) do { \
    ACC = fdot2(bch((V).x), bch((W4).x), ACC); \
    ACC = fdot2(bch((V).y), bch((W4).y), ACC); \
    ACC = fdot2(bch((V).z), bch((W4).z), ACC); \
    ACC = fdot2(bch((V).w), bch((W4).w), ACC); } while (0)

// ======================= 2-elements-per-block kernel =======================
__global__ __launch_bounds__(256, 2)
void darnn2_kernel(
    const float* __restrict__ x,
    const float* __restrict__ eWih, const float* __restrict__ eWhh,
    const float* __restrict__ ebih, const float* __restrict__ ebhh,
    const float* __restrict__ elv,  const float* __restrict__ elw,
    const float* __restrict__ elwb, const float* __restrict__ elu,
    const float* __restrict__ elub,
    const float* __restrict__ dWih, const float* __restrict__ dWhh,
    const float* __restrict__ dbih, const float* __restrict__ dbhh,
    const float* __restrict__ dlv,  const float* __restrict__ dlw,
    const float* __restrict__ dlwb, const float* __restrict__ dlu,
    const float* __restrict__ dlub, const float* __restrict__ dlp,
    const float* __restrict__ dlpb, const float* __restrict__ dly,
    const float* __restrict__ dlyb, const int* __restrict__ tgtp,
    h2t* __restrict__ hsg_all,
    float* __restrict__ out)
{
    // Transposed attention-precompute pool (raw, unscaled):
    //   enc: s_pool2[wp*98 + n]  wp in [0,64), n in [0,96)  ({h2A,h2B} pair values)
    //   dec: s_pool2[ep*130 + w] ep in [0,32), w in [0,128)
    __shared__ __align__(16) f2t  s_pool2[64 * 98];      // 50176 B
    __shared__ __align__(16) f4t  s_wo4[64];             // {woA0,woA1,woB0,woB1} (CLOG-scaled)
    __shared__ __align__(16) f2t  s_lv[64];              // lv pairs (dec: dlv in [0..31])
    __shared__ __align__(16) f2t  s_soft2[128];          // {eA,eB} (dec only)
    __shared__ __align__(16) char s_u2v[2048];           // enc: xtA/xtB (unnormalized)
    __shared__ __align__(16) h2t  s_hch2[2][2][64];      // [pp][el][h|c pairs]
    __shared__ __align__(16) f4t  s_spw[4][256];         // eWih pairs 32..47 (per tid)
    __shared__ __align__(16) f4t  s_sph[2][256];         // eWhh (dec: dWhh) pairs 24..31
    __shared__ __align__(16) f2t  s_psum[4];             // per-wave exp-sum partials
    __shared__ __align__(16) f2t  s_ytp[4];              // per-wave y-tilde partials (dec)
    __shared__ float s_scal[8];

    h2t*  const s_xtA  = (h2t*)s_u2v;
    h2t*  const s_xtB  = (h2t*)(s_u2v + 1024);

    const int tid  = threadIdx.x;
    const int b    = blockIdx.x;
    const int lane = tid & 63, wq = tid >> 6;
    const int uidx = wq * 16 + (lane >> 2);
    const int jrow = (lane & 3) * 64 + uidx;
    const float* xbA = x + (size_t)(2 * b) * NV * WW;
    const float* xbB = xbA + NV * WW;
    h2t* hsgP = hsg_all + (size_t)b * (WW * 64);   // [w][32 k][2 el]

    float c_regA = 0.f, c_regB = 0.f;

    // ---------------- init ----------------
    if (tid < 64) {
        s_hch2[0][0][tid] = pk2(0.f, 0.f);
        s_hch2[0][1][tid] = pk2(0.f, 0.f);
        f2t lv = { elv[2 * tid], elv[2 * tid + 1] };
        s_lv[tid] = lv;
    }

    // ---------------- phase A: u_e (raw fp16, transposed) ----------------
    {
        const int o = tid >> 1, p = tid & 1;
        f4t lu4[16];
        const f4t* lur = (const f4t*)(elu + o * WW + p * 64);
#pragma unroll
        for (int i = 0; i < 16; ++i) lu4[i] = lur[i];
        const float lub_o = elub[o];
        for (int n = 0; n < NV; ++n) {
            const f4t* xrA = (const f4t*)(xbA + n * WW + p * 64);
            const f4t* xrB = (const f4t*)(xbB + n * WW + p * 64);
            float aA = 0.f, aB = 0.f;
#pragma unroll
            for (int i = 0; i < 16; ++i) {
                f4t vA = xrA[i], vB = xrB[i], l4 = lu4[i];
                aA = fmaf(vA.x, l4.x, aA); aA = fmaf(vA.y, l4.y, aA);
                aA = fmaf(vA.z, l4.z, aA); aA = fmaf(vA.w, l4.w, aA);
                aB = fmaf(vB.x, l4.x, aB); aB = fmaf(vB.y, l4.y, aB);
                aB = fmaf(vB.z, l4.z, aB); aB = fmaf(vB.w, l4.w, aB);
            }
            aA += __shfl_xor(aA, 1, 64);
            aB += __shfl_xor(aB, 1, 64);
            float valA = aA + lub_o;
            float valB = aB + lub_o;
            float vnA = __shfl_xor(valA, 2, 64);
            float vnB = __shfl_xor(valB, 2, 64);
            if (!(tid & 3)) {
                const int op = tid >> 2;
                f2t st = { bcf(pk2(valA, vnA)), bcf(pk2(valB, vnB)) };
                s_pool2[op * 98 + n] = st;
            }
        }
    }
    __syncthreads();
    __builtin_amdgcn_sched_barrier(0);

    float elvsum;
    { f2t lv = s_lv[lane]; elvsum = wsum(lv.x + lv.y); }

    // ---------------- encoder weights ----------------
    h2t lw_r[32];
    {
        const f2t* r = (const f2t*)(elw + (tid >> 1) * 128 + (tid & 1) * 64);
#pragma unroll
        for (int i = 0; i < 32; ++i) { f2t v = r[i]; lw_r[i] = pk2(v.x, v.y); }
    }
    const float lwb_r = elwb[tid >> 1];
    h2t wih_r[32];
    {
        const f2t* r = (const f2t*)(eWih + jrow * 96);
#pragma unroll
        for (int i = 0; i < 32; ++i) { f2t v = r[i]; wih_r[i] = pk2(v.x, v.y); }
#pragma unroll
        for (int g = 0; g < 4; ++g) {
            f4t ws;
            { f2t v = r[32 + 4*g];     ws.x = bcf(pk2(v.x, v.y)); }
            { f2t v = r[33 + 4*g];     ws.y = bcf(pk2(v.x, v.y)); }
            { f2t v = r[34 + 4*g];     ws.z = bcf(pk2(v.x, v.y)); }
            { f2t v = r[35 + 4*g];     ws.w = bcf(pk2(v.x, v.y)); }
            s_spw[g][tid] = ws;
        }
    }
    h2t whh_r[24];
    {
        const f2t* r = (const f2t*)(eWhh + jrow * 64);
#pragma unroll
        for (int i = 0; i < 24; ++i) { f2t v = r[i]; whh_r[i] = pk2(v.x, v.y); }
#pragma unroll
        for (int g = 0; g < 2; ++g) {
            f4t ws;
            { f2t v = r[24 + 4*g];     ws.x = bcf(pk2(v.x, v.y)); }
            { f2t v = r[25 + 4*g];     ws.y = bcf(pk2(v.x, v.y)); }
            { f2t v = r[26 + 4*g];     ws.z = bcf(pk2(v.x, v.y)); }
            { f2t v = r[27 + 4*g];     ws.w = bcf(pk2(v.x, v.y)); }
            s_sph[g][tid] = ws;
        }
    }
    const float bsum_r = ebih[jrow] + ebhh[jrow];
    __builtin_amdgcn_sched_barrier(0);

    // ---------------- encoder recurrence: 3 barriers/step ----------------
#pragma unroll 1
    for (int t = 0; t < WW; ++t) {
        const int pp = t & 1;
        float xvA = 0.f, xvB = 0.f;
        if (!(tid & 1) && tid < 192) {
            const int n = tid >> 1;
            xvA = xbA[n * WW + t]; xvB = xbB[n * WW + t];
        }
        // ph1: w_out both elements
        {
            const f4t* hcA = (const f4t*)&s_hch2[pp][0][(tid & 1) * 32];
            const f4t* hcB = (const f4t*)&s_hch2[pp][1][(tid & 1) * 32];
            float aA = 0.f, aB = 0.f;
#pragma unroll
            for (int i = 0; i < 8; ++i) {
                f4t vA = hcA[i], vB = hcB[i];
                DOT4(vA, lw_r, 4 * i, aA);
                DOT4(vB, lw_r, 4 * i, aB);
            }
            aA += __shfl_xor(aA, 1, 64); aB += __shfl_xor(aB, 1, 64);
            float woA = (aA + lwb_r) * CLOG, woB = (aB + lwb_r) * CLOG;
            float wnA = __shfl_xor(woA, 2, 64), wnB = __shfl_xor(woB, 2, 64);
            if (!(tid & 3)) { f4t st = {woA, wnA, woB, wnB}; s_wo4[tid >> 2] = st; }
        }
        __syncthreads();
        // ph2: scores + exp + unnormalized x_tilde + per-wave exp-sum partials
        float prodA = 0.f, prodB = 0.f, eA = 0.f, eB = 0.f;
        if (tid < 192) {
            const int n = tid >> 1, part = tid & 1;
            const f4t* wor = s_wo4 + part * 32;
            const f2t* lvr = s_lv + part * 32;
            const f2t* uer = s_pool2 + part * 32 * 98 + n;
            float aA = 0.f, aB = 0.f;
#pragma unroll
            for (int j = 0; j < 32; ++j) {
                f4t w4 = wor[j];
                f2t lv = lvr[j];
                f2t up = uer[j * 98];
                h2t uA = bch(up.x), uB = bch(up.y);
                float g0A = fmaf((float)uA.x, CLOG, w4.x);
                float g1A = fmaf((float)uA.y, CLOG, w4.y);
                float g0B = fmaf((float)uB.x, CLOG, w4.z);
                float g1B = fmaf((float)uB.y, CLOG, w4.w);
                float r0A = rcp_(ex2(g0A) + 1.f);
                float r1A = rcp_(ex2(g1A) + 1.f);
                float r0B = rcp_(ex2(g0B) + 1.f);
                float r1B = rcp_(ex2(g1B) + 1.f);
                aA = fmaf(lv.x, r0A, aA); aA = fmaf(lv.y, r1A, aA);
                aB = fmaf(lv.x, r0B, aB); aB = fmaf(lv.y, r1B, aB);
            }
            aA += __shfl_xor(aA, 1, 64); aB += __shfl_xor(aB, 1, 64);
            if (!(tid & 1)) {
                eA = ex2((elvsum - 2.f * aA) * L2E);
                eB = ex2((elvsum - 2.f * aB) * L2E);
                prodA = eA * xvA; prodB = eB * xvB;
            }
        }
        // unnormalized x_tilde pairs
        {
            float p1A = __shfl_xor(prodA, 2, 64), p1B = __shfl_xor(prodB, 2, 64);
            if (tid < 192 && !(tid & 3)) {
                s_xtA[tid >> 2] = pk2(prodA, p1A);
                s_xtB[tid >> 2] = pk2(prodB, p1B);
            }
        }
        // per-wave exp-sum partials (wave 3 contributes zeros)
        {
            float sA = eA, sB = eB;
#pragma unroll
            for (int o = 32; o; o >>= 1) { sA += __shfl_xor(sA, o, 64); sB += __shfl_xor(sB, o, 64); }
            if (lane == 0) { f2t st = {sA, sB}; s_psum[wq] = st; }
        }
        __syncthreads();
        // ph4: inv from partials, gates (split accumulators), fused LSTM update
        {
            f2t q0 = s_psum[0], q1 = s_psum[1], q2 = s_psum[2], q3 = s_psum[3];
            const float invA = rcp_(q0.x + q1.x + q2.x + q3.x);
            const float invB = rcp_(q0.y + q1.y + q2.y + q3.y);
            float gxA = 0.f, gxB = 0.f, ghA = bsum_r, ghB = bsum_r;
            const f4t* xtA4 = (const f4t*)s_xtA;
            const f4t* xtB4 = (const f4t*)s_xtB;
#pragma unroll
            for (int i = 0; i < 8; ++i) {
                f4t vA = xtA4[i], vB = xtB4[i];
                DOT4(vA, wih_r, 4 * i, gxA);
                DOT4(vB, wih_r, 4 * i, gxB);
            }
#pragma unroll
            for (int g = 0; g < 4; ++g) {
                f4t w = s_spw[g][tid];
                f4t vA = xtA4[8 + g], vB = xtB4[8 + g];
                DOT4W(vA, w, gxA); DOT4W(vB, w, gxB);
            }
            const f4t* hA4 = (const f4t*)&s_hch2[pp][0][0];
            const f4t* hB4 = (const f4t*)&s_hch2[pp][1][0];
#pragma unroll
            for (int i = 0; i < 6; ++i) {
                f4t vA = hA4[i], vB = hB4[i];
                DOT4(vA, whh_r, 4 * i, ghA);
                DOT4(vB, whh_r, 4 * i, ghB);
            }
#pragma unroll
            for (int g = 0; g < 2; ++g) {
                f4t w = s_sph[g][tid];
                f4t vA = hA4[6 + g], vB = hB4[6 + g];
                DOT4W(vA, w, ghA); DOT4W(vB, w, ghB);
            }
            float gA = fmaf(gxA, invA, ghA);
            float gB = fmaf(gxB, invB, ghB);
            const int base = lane & ~3;
            float giA = __shfl(gA, base, 64),     giB = __shfl(gB, base, 64);
            float gfA = __shfl(gA, base + 1, 64), gfB = __shfl(gB, base + 1, 64);
            float g2A = __shfl(gA, base + 2, 64), g2B = __shfl(gB, base + 2, 64);
            float goA = __shfl(gA, base + 3, 64), goB = __shfl(gB, base + 3, 64);
            float cA = sig_c(gfA) * c_regA + sig_c(giA) * tanh_c(g2A);
            float cB = sig_c(gfB) * c_regB + sig_c(giB) * tanh_c(g2B);
            float hA = sig_c(goA) * tanh_c(cA);
            float hB = sig_c(goB) * tanh_c(cB);
            c_regA = cA; c_regB = cB;
            float hnA = __shfl_xor(hA, 4, 64), cnA = __shfl_xor(cA, 4, 64);
            float hnB = __shfl_xor(hB, 4, 64), cnB = __shfl_xor(cB, 4, 64);
            if (!(lane & 7)) {
                const int k = wq * 8 + (lane >> 3);
                h2t phA = pk2(hA, hnA), phB = pk2(hB, hnB);
                s_hch2[pp ^ 1][0][k]      = phA;
                s_hch2[pp ^ 1][0][32 + k] = pk2(cA, cnA);
                s_hch2[pp ^ 1][1][k]      = phB;
                s_hch2[pp ^ 1][1][32 + k] = pk2(cB, cnB);
                f2t st = { bcf(phA), bcf(phB) };
                *(f2t*)&hsgP[t * 64 + k * 2] = st;
            }
        }
        __syncthreads();
    }

    // ---------------- u_d = h_seq @ dlu^T + dlub (raw, transposed) ----------------
    {
        const int e2h = tid & 31;
        h2t du0[32], du1[32];
        {
            const f4t* p0 = (const f4t*)(dlu + (2 * e2h) * 64);
            const f4t* p1 = (const f4t*)(dlu + (2 * e2h + 1) * 64);
#pragma unroll
            for (int i = 0; i < 16; ++i) {
                f4t v0 = p0[i], v1 = p1[i];
                du0[2 * i] = pk2(v0.x, v0.y); du0[2 * i + 1] = pk2(v0.z, v0.w);
                du1[2 * i] = pk2(v1.x, v1.y); du1[2 * i + 1] = pk2(v1.z, v1.w);
            }
        }
        const float b0 = dlub[2 * e2h], b1 = dlub[2 * e2h + 1];
#pragma unroll 1
        for (int pass = 0; pass < 16; ++pass) {
            const int w = pass * 8 + (tid >> 5);
            float a0A = b0, a1A = b1, a0B = b0, a1B = b1;
            const f4t* hr = (const f4t*)(hsgP + w * 64);
#pragma unroll
            for (int i = 0; i < 16; ++i) {
                f4t v = hr[i];
                a0A = fdot2(bch(v.x), du0[2*i], a0A); a0A = fdot2(bch(v.z), du0[2*i+1], a0A);
                a1A = fdot2(bch(v.x), du1[2*i], a1A); a1A = fdot2(bch(v.z), du1[2*i+1], a1A);
                a0B = fdot2(bch(v.y), du0[2*i], a0B); a0B = fdot2(bch(v.w), du0[2*i+1], a0B);
                a1B = fdot2(bch(v.y), du1[2*i], a1B); a1B = fdot2(bch(v.w), du1[2*i+1], a1B);
            }
            f2t st = { bcf(pk2(a0A, a1A)), bcf(pk2(a0B, a1B)) };
            s_pool2[e2h * 130 + w] = st;
        }
    }
    __builtin_amdgcn_sched_barrier(0);

    // ---------------- decoder setup ----------------
    const int tgt = tgtp[0];
    if (tid < 32) { f2t lv = { dlv[2 * tid], dlv[2 * tid + 1] }; s_lv[tid] = lv; }
    if (tid < 64) {
        s_hch2[0][0][tid] = pk2(0.f, 0.f);
        s_hch2[0][1][tid] = pk2(0.f, 0.f);
    }
    float dlvsum;
    { float v = dlv[lane]; dlvsum = wsum(v); }
    h2t dlw_r[16];
    {
        const f2t* r = (const f2t*)(dlw + (tid >> 2) * 128 + (tid & 3) * 32);
#pragma unroll
        for (int i = 0; i < 16; ++i) { f2t v = r[i]; dlw_r[i] = pk2(v.x, v.y); }
    }
    const float dlwb_r = dlwb[tid >> 2];
    h2t dwhh_r[24];
    {
        const f2t* r = (const f2t*)(dWhh + jrow * 64);
#pragma unroll
        for (int i = 0; i < 24; ++i) { f2t v = r[i]; dwhh_r[i] = pk2(v.x, v.y); }
#pragma unroll
        for (int g = 0; g < 2; ++g) {
            f4t ws;
            { f2t v = r[24 + 4*g]; ws.x = bcf(pk2(v.x, v.y)); }
            { f2t v = r[25 + 4*g]; ws.y = bcf(pk2(v.x, v.y)); }
            { f2t v = r[26 + 4*g]; ws.z = bcf(pk2(v.x, v.y)); }
            { f2t v = r[27 + 4*g]; ws.w = bcf(pk2(v.x, v.y)); }
            s_sph[g][tid] = ws;
        }
    }
    const float dwih_r  = dWih[jrow];
    const float dbsum_r = dbih[jrow] + dbhh[jrow];
    const float lp0     = dlp[0];
    const h2t   lp1p    = pk2(dlp[1 + 2 * (tid & 31)], dlp[2 + 2 * (tid & 31)]);
    const float lpb     = dlpb[0];
    c_regA = 0.f; c_regB = 0.f;
    float h_regA = 0.f, h_regB = 0.f;
    __syncthreads();

    // ---------------- decoder recurrence: 4 barriers/step ----------------
#pragma unroll 1
    for (int s = 0; s < WW - 1; ++s) {
        const int pp = s & 1;
        const float ysA = xbA[(size_t)tgt * WW + s];
        const float ysB = xbB[(size_t)tgt * WW + s];
        // ph1': w_out_d both elements
        {
            const f4t* hcA = (const f4t*)&s_hch2[pp][0][(tid & 3) * 16];
            const f4t* hcB = (const f4t*)&s_hch2[pp][1][(tid & 3) * 16];
            float aA = 0.f, aB = 0.f;
#pragma unroll
            for (int i = 0; i < 4; ++i) {
                f4t vA = hcA[i], vB = hcB[i];
                DOT4(vA, dlw_r, 4 * i, aA);
                DOT4(vB, dlw_r, 4 * i, aB);
            }
            aA += __shfl_xor(aA, 1, 64); aB += __shfl_xor(aB, 1, 64);
            aA += __shfl_xor(aA, 2, 64); aB += __shfl_xor(aB, 2, 64);
            float woA = (aA + dlwb_r) * CLOG, woB = (aB + dlwb_r) * CLOG;
            float wnA = __shfl_xor(woA, 4, 64), wnB = __shfl_xor(woB, 4, 64);
            if (!(tid & 7)) { f4t st = {woA, wnA, woB, wnB}; s_wo4[tid >> 3] = st; }
        }
        __syncthreads();
        // ph2': v scores + exp + per-wave exp-sum partials
        {
            const int w = tid >> 1, part = tid & 1;
            const f4t* wor = s_wo4 + part * 16;
            const f2t* lvr = s_lv + part * 16;
            const f2t* udr = s_pool2 + part * 16 * 130 + w;
            float aA = 0.f, aB = 0.f;
#pragma unroll
            for (int j = 0; j < 16; ++j) {
                f4t w4 = wor[j];
                f2t lv = lvr[j];
                f2t up = udr[j * 130];
                h2t uA = bch(up.x), uB = bch(up.y);
                float g0A = fmaf((float)uA.x, CLOG, w4.x);
                float g1A = fmaf((float)uA.y, CLOG, w4.y);
                float g0B = fmaf((float)uB.x, CLOG, w4.z);
                float g1B = fmaf((float)uB.y, CLOG, w4.w);
                float r0A = rcp_(ex2(g0A) + 1.f);
                float r1A = rcp_(ex2(g1A) + 1.f);
                float r0B = rcp_(ex2(g0B) + 1.f);
                float r1B = rcp_(ex2(g1B) + 1.f);
                aA = fmaf(lv.x, r0A, aA); aA = fmaf(lv.y, r1A, aA);
                aB = fmaf(lv.x, r0B, aB); aB = fmaf(lv.y, r1B, aB);
            }
            aA += __shfl_xor(aA, 1, 64); aB += __shfl_xor(aB, 1, 64);
            float eA = 0.f, eB = 0.f;
            if (!(tid & 1)) {
                eA = ex2((dlvsum - 2.f * aA) * L2E);
                eB = ex2((dlvsum - 2.f * aB) * L2E);
                f2t st = {eA, eB}; s_soft2[w] = st;
            }
            float sA = eA, sB = eB;
#pragma unroll
            for (int o = 32; o; o >>= 1) { sA += __shfl_xor(sA, o, 64); sB += __shfl_xor(sB, o, 64); }
            if (lane == 0) { f2t st = {sA, sB}; s_psum[wq] = st; }
        }
        __syncthreads();
        // ph3': fused context -> y_tilde partials (per-wave)
        {
            const int e2 = tid & 31, pg = tid >> 5;
            float ytA = 0.f, ytB = 0.f;
#pragma unroll
            for (int j = 0; j < 16; ++j) {
                const int w = pg * 16 + j;
                f2t be = s_soft2[w];
                f2t hp = *(const f2t*)&hsgP[w * 64 + e2 * 2];
                h2t hA = bch(hp.x), hB = bch(hp.y);
                ytA = fmaf(be.x, fdot2(hA, lp1p, 0.f), ytA);
                ytB = fmaf(be.y, fdot2(hB, lp1p, 0.f), ytB);
            }
#pragma unroll
            for (int o = 32; o; o >>= 1) { ytA += __shfl_xor(ytA, o, 64); ytB += __shfl_xor(ytB, o, 64); }
            if (lane == 0) { f2t st = {ytA, ytB}; s_ytp[wq] = st; }
        }
        __syncthreads();
        // ph4': y_tilde + gates + update
        {
            f2t q0 = s_psum[0], q1 = s_psum[1], q2 = s_psum[2], q3 = s_psum[3];
            f2t y0 = s_ytp[0],  y1 = s_ytp[1],  y2 = s_ytp[2],  y3 = s_ytp[3];
            const float invA = rcp_(q0.x + q1.x + q2.x + q3.x);
            const float invB = rcp_(q0.y + q1.y + q2.y + q3.y);
            float ytA = fmaf(ysA, lp0, (y0.x + y1.x + y2.x + y3.x) * invA + lpb);
            float ytB = fmaf(ysB, lp0, (y0.y + y1.y + y2.y + y3.y) * invB + lpb);
            float gA = fmaf(ytA, dwih_r, dbsum_r);
            float gB = fmaf(ytB, dwih_r, dbsum_r);
            const f4t* hA4 = (const f4t*)&s_hch2[pp][0][0];
            const f4t* hB4 = (const f4t*)&s_hch2[pp][1][0];
#pragma unroll
            for (int i = 0; i < 6; ++i) {
                f4t vA = hA4[i], vB = hB4[i];
                DOT4(vA, dwhh_r, 4 * i, gA);
                DOT4(vB, dwhh_r, 4 * i, gB);
            }
#pragma unroll
            for (int g = 0; g < 2; ++g) {
                f4t w = s_sph[g][tid];
                f4t vA = hA4[6 + g], vB = hB4[6 + g];
                DOT4W(vA, w, gA); DOT4W(vB, w, gB);
            }
            const int base = lane & ~3;
            float giA = __shfl(gA, base, 64),     giB = __shfl(gB, base, 64);
            float gfA = __shfl(gA, base + 1, 64), gfB = __shfl(gB, base + 1, 64);
            float g2A = __shfl(gA, base + 2, 64), g2B = __shfl(gB, base + 2, 64);
            float goA = __shfl(gA, base + 3, 64), goB = __shfl(gB, base + 3, 64);
            float cA = sig_c(gfA) * c_regA + sig_c(giA) * tanh_c(g2A);
            float cB = sig_c(gfB) * c_regB + sig_c(giB) * tanh_c(g2B);
            float hA = sig_c(goA) * tanh_c(cA);
            float hB = sig_c(goB) * tanh_c(cB);
            c_regA = cA; c_regB = cB; h_regA = hA; h_regB = hB;
            float hnA = __shfl_xor(hA, 4, 64), cnA = __shfl_xor(cA, 4, 64);
            float hnB = __shfl_xor(hB, 4, 64), cnB = __shfl_xor(cB, 4, 64);
            if (!(lane & 7)) {
                const int k = wq * 8 + (lane >> 3);
                s_hch2[pp ^ 1][0][k]      = pk2(hA, hnA);
                s_hch2[pp ^ 1][0][32 + k] = pk2(cA, cnA);
                s_hch2[pp ^ 1][1][k]      = pk2(hB, hnB);
                s_hch2[pp ^ 1][1][32 + k] = pk2(cB, cnB);
            }
        }
        __syncthreads();
    }

    // ---------------- output ----------------
    {
        float termA = 0.f, termB = 0.f;
        if (!(lane & 3)) {
            termA = h_regA * dly[uidx] + c_regA * dly[64 + uidx];
            termB = h_regB * dly[uidx] + c_regB * dly[64 + uidx];
        }
#pragma unroll
        for (int o = 32; o; o >>= 1) {
            termA += __shfl_xor(termA, o, 64);
            termB += __shfl_xor(termB, o, 64);
        }
        if (lane == 0) { s_scal[wq] = termA; s_scal[4 + wq] = termB; }
    }
    __syncthreads();
    if (tid == 0) out[2 * b]     = s_scal[0] + s_scal[1] + s_scal[2] + s_scal[3] + dlyb[0];
    if (tid == 1) out[2 * b + 1] = s_scal[4] + s_scal[5] + s_scal[6] + s_scal[7] + dlyb[0];
}

// ======================= fallback: r4 1-element kernel (LDS h_seq) ========
__global__ __launch_bounds__(256, 2)
void darnn1_kernel(
    const float* __restrict__ x,
    const float* __restrict__ eWih, const float* __restrict__ eWhh,
    const float* __restrict__ ebih, const float* __restrict__ ebhh,
    const float* __restrict__ elv,  const float* __restrict__ elw,
    const float* __restrict__ elwb, const float* __restrict__ elu,
    const float* __restrict__ elub,
    const float* __restrict__ dWih, const float* __restrict__ dWhh,
    const float* __restrict__ dbih, const float* __restrict__ dbhh,
    const float* __restrict__ dlv,  const float* __restrict__ dlw,
    const float* __restrict__ dlwb, const float* __restrict__ dlu,
    const float* __restrict__ dlub, const float* __restrict__ dlp,
    const float* __restrict__ dlpb, const float* __restrict__ dly,
    const float* __restrict__ dlyb, const int* __restrict__ tgtp,
    float* __restrict__ out)
{
    __shared__ __align__(16) h2t  s_pool[96 * 64];
    __shared__ __align__(16) h2t  s_hseq2[WW][32];
    __shared__ __align__(16) f4t  s_wlv[64];
    __shared__ __align__(16) char s_u2[1024];
    __shared__ __align__(16) float s_soft[128];
    __shared__ __align__(16) h2t  s_hch2[2][64];
    __shared__ __align__(16) f4t  s_spillh[2][256];
    __shared__ __align__(16) f4t  s_spillw[256];

    float* s_wlvf = (float*)s_wlv;
    h2t*  const s_xt  = (h2t*)s_u2;
    float* const s_tmp = (float*)s_u2;

    const int tid  = threadIdx.x;
    const int b    = blockIdx.x;
    const int lane = tid & 63, wq = tid >> 6;
    const int uidx = wq * 16 + (lane >> 2);
    const int jrow = (lane & 3) * 64 + uidx;
    const float* xb = x + (size_t)b * NV * WW;

    float c_reg = 0.f;

    if (tid >= 96 && tid < 128) s_soft[tid] = 0.f;
    if (tid < 64) {
        s_hch2[0][tid] = pk2(0.f, 0.f);
        s_wlvf[tid * 4 + 2] = elv[2 * tid];
        s_wlvf[tid * 4 + 3] = elv[2 * tid + 1];
    }
    {
        const int o = tid >> 1, p = tid & 1;
        f4t lu4[16];
        const f4t* lur = (const f4t*)(elu + o * WW + p * 64);
#pragma unroll
        for (int i = 0; i < 16; ++i) lu4[i] = lur[i];
        const float lub_o = elub[o];
        for (int n = 0; n < NV; ++n) {
            const f4t* xr = (const f4t*)(xb + n * WW + p * 64);
            float a = 0.f;
#pragma unroll
            for (int i = 0; i < 16; ++i) {
                f4t v = xr[i], l4 = lu4[i];
                a = fmaf(v.x, l4.x, a); a = fmaf(v.y, l4.y, a);
                a = fmaf(v.z, l4.z, a); a = fmaf(v.w, l4.w, a);
            }
            a += __shfl_xor(a, 1, 64);
            float val = (a + lub_o) * CLOG;
            float vn  = __shfl_xor(val, 2, 64);
            if (!(tid & 3)) s_pool[n * 64 + ((tid >> 2) ^ (n & 31))] = pk2(val, vn);
        }
    }
    __syncthreads();
    __builtin_amdgcn_sched_barrier(0);

    float elvsum;
    {
        const f2t lvp = *(const f2t*)&s_wlvf[(tid & 63) * 4 + 2];
        elvsum = wsum(lvp.x + lvp.y);
    }
    h2t lw_r[32];
    {
        const f2t* r = (const f2t*)(elw + (tid >> 1) * 128 + (tid & 1) * 64);
#pragma unroll
        for (int i = 0; i < 32; ++i) { f2t v = r[i]; lw_r[i] = pk2(v.x, v.y); }
    }
    const float lwb_r = elwb[tid >> 1];
    h2t wih_r[44];
    {
        const f2t* r = (const f2t*)(eWih + jrow * 96);
#pragma unroll
        for (int i = 0; i < 44; ++i) { f2t v = r[i]; wih_r[i] = pk2(v.x, v.y); }
        f4t ws;
        { f2t v = r[44]; ws.x = bcf(pk2(v.x, v.y)); }
        { f2t v = r[45]; ws.y = bcf(pk2(v.x, v.y)); }
        { f2t v = r[46]; ws.z = bcf(pk2(v.x, v.y)); }
        { f2t v = r[47]; ws.w = bcf(pk2(v.x, v.y)); }
        s_spillw[tid] = ws;
    }
    h2t whh_r[24];
    {
        const f2t* r = (const f2t*)(eWhh + jrow * 64);
#pragma unroll
        for (int i = 0; i < 24; ++i) { f2t v = r[i]; whh_r[i] = pk2(v.x, v.y); }
        f4t w0, w1;
        { f2t v = r[24]; w0.x = bcf(pk2(v.x, v.y)); }
        { f2t v = r[25]; w0.y = bcf(pk2(v.x, v.y)); }
        { f2t v = r[26]; w0.z = bcf(pk2(v.x, v.y)); }
        { f2t v = r[27]; w0.w = bcf(pk2(v.x, v.y)); }
        { f2t v = r[28]; w1.x = bcf(pk2(v.x, v.y)); }
        { f2t v = r[29]; w1.y = bcf(pk2(v.x, v.y)); }
        { f2t v = r[30]; w1.z = bcf(pk2(v.x, v.y)); }
        { f2t v = r[31]; w1.w = bcf(pk2(v.x, v.y)); }
        s_spillh[0][tid] = w0;
        s_spillh[1][tid] = w1;
    }
    const float bsum_r = ebih[jrow] + ebhh[jrow];
    __builtin_amdgcn_sched_barrier(0);

#pragma unroll 1
    for (int t = 0; t < WW; ++t) {
        const int pp = t & 1;
        float xv = 0.f;
        if (!(tid & 1) && tid < 192) xv = xb[(tid >> 1) * WW + t];
        {
            const f4t* hc4 = (const f4t*)&s_hch2[pp][(tid & 1) * 32];
            float a = 0.f;
#pragma unroll
            for (int i = 0; i < 8; ++i) { f4t v = hc4[i]; DOT4(v, lw_r, 4 * i, a); }
            a += __shfl_xor(a, 1, 64);
            float wo = (a + lwb_r) * CLOG;
            float wn = __shfl_xor(wo, 2, 64);
            if (!(tid & 3)) { f2t st = {wo, wn}; *(f2t*)&s_wlvf[(tid >> 2) * 4] = st; }
        }
        __syncthreads();
        float prod = 0.f;
        if (tid < 192) {
            const int n = tid >> 1, sw = n & 31;
            const h2t* uer = s_pool + n * 64;
            float a = 0.f;
#pragma unroll
            for (int j = 0; j < 32; ++j) {
                const int wp = (tid & 1) * 32 + j;
                f4t wl = s_wlv[wp];
                h2t u  = uer[wp ^ sw];
                float r0 = rcp_(ex2(wl.x + (float)u.x) + 1.f);
                float r1 = rcp_(ex2(wl.y + (float)u.y) + 1.f);
                a = fmaf(wl.z, r0, a);
                a = fmaf(wl.w, r1, a);
            }
            a += __shfl_xor(a, 1, 64);
            if (!(tid & 1)) {
                float e = ex2((elvsum - 2.f * a) * L2E);
                prod = e * xv;
                s_soft[tid >> 1] = e;
            }
        }
        __syncthreads();
        if (tid < 192) {
            const int l = tid & 63;
            float sm = s_soft[l] + s_soft[64 + l];
            sm = wsum(sm);
            float inv = rcp_(sm);
            float p1 = __shfl_xor(prod, 2, 64);
            if (!(tid & 3)) s_xt[tid >> 2] = pk2(prod * inv, p1 * inv);
        }
        __syncthreads();
        {
            float gv = bsum_r;
            const f4t* xt4 = (const f4t*)s_xt;
#pragma unroll
            for (int i = 0; i < 11; ++i) { f4t v = xt4[i]; DOT4(v, wih_r, 4 * i, gv); }
            { f4t v = xt4[11]; f4t w = s_spillw[tid]; DOT4W(v, w, gv); }
            const f4t* h4 = (const f4t*)&s_hch2[pp][0];
#pragma unroll
            for (int i = 0; i < 6; ++i) { f4t v = h4[i]; DOT4(v, whh_r, 4 * i, gv); }
            { f4t v = h4[6]; f4t w = s_spillh[0][tid]; DOT4W(v, w, gv); }
            { f4t v = h4[7]; f4t w = s_spillh[1][tid]; DOT4W(v, w, gv); }
            const int base = lane & ~3;
            float gi = __shfl(gv, base, 64);
            float gf = __shfl(gv, base + 1, 64);
            float g2 = __shfl(gv, base + 2, 64);
            float go = __shfl(gv, base + 3, 64);
            float c = sig_c(gf) * c_reg + sig_c(gi) * tanh_c(g2);
            float h = sig_c(go) * tanh_c(c);
            c_reg = c;
            float hn = __shfl_xor(h, 4, 64);
            float cn = __shfl_xor(c, 4, 64);
            if (!(lane & 7)) {
                const int k = wq * 8 + (lane >> 3);
                s_hch2[pp ^ 1][k]      = pk2(h, hn);
                s_hch2[pp ^ 1][32 + k] = pk2(c, cn);
                s_hseq2[t][k ^ (t & 31)] = pk2(h, hn);
            }
        }
        __syncthreads();
    }
    {
        const int e2h = tid & 31;
        h2t du0[32], du1[32];
        {
            const f4t* p0 = (const f4t*)(dlu + (2 * e2h) * 64);
            const f4t* p1 = (const f4t*)(dlu + (2 * e2h + 1) * 64);
#pragma unroll
            for (int i = 0; i < 16; ++i) {
                f4t v0 = p0[i], v1 = p1[i];
                du0[2 * i] = pk2(v0.x, v0.y); du0[2 * i + 1] = pk2(v0.z, v0.w);
                du1[2 * i] = pk2(v1.x, v1.y); du1[2 * i + 1] = pk2(v1.z, v1.w);
            }
        }
        const float b0 = dlub[2 * e2h], b1 = dlub[2 * e2h + 1];
#pragma unroll 1
        for (int pass = 0; pass < 16; ++pass) {
            const int w = pass * 8 + (tid >> 5);
            float a0 = b0, a1 = b1;
            const int sww = w & 31;
#pragma unroll
            for (int i = 0; i < 32; ++i) {
                h2t hp = s_hseq2[w][i ^ sww];
                a0 = fdot2(hp, du0[i], a0);
                a1 = fdot2(hp, du1[i], a1);
            }
            s_pool[w * 32 + (e2h ^ (w & 31))] = pk2(a0 * CLOG, a1 * CLOG);
        }
    }
    __builtin_amdgcn_sched_barrier(0);

    const int tgt = tgtp[0];
    if (tid < 32) {
        s_wlvf[tid * 4 + 2] = dlv[2 * tid];
        s_wlvf[tid * 4 + 3] = dlv[2 * tid + 1];
    }
    if (tid < 64) s_hch2[0][tid] = pk2(0.f, 0.f);
    float dlvsum;
    { float v = dlv[tid & 63]; dlvsum = wsum(v); }
    h2t dlw_r[16];
    {
        const f2t* r = (const f2t*)(dlw + (tid >> 2) * 128 + (tid & 3) * 32);
#pragma unroll
        for (int i = 0; i < 16; ++i) { f2t v = r[i]; dlw_r[i] = pk2(v.x, v.y); }
    }
    const float dlwb_r = dlwb[tid >> 2];
    h2t dwhh_r[32];
    {
        const f2t* r = (const f2t*)(dWhh + jrow * 64);
#pragma unroll
        for (int i = 0; i < 32; ++i) { f2t v = r[i]; dwhh_r[i] = pk2(v.x, v.y); }
    }
    const float dwih_r  = dWih[jrow];
    const float dbsum_r = dbih[jrow] + dbhh[jrow];
    const float lp0     = dlp[0];
    const float lp1_r   = dlp[1 + (tid & 63)];
    const float lpb     = dlpb[0];
    c_reg = 0.f;
    float h_reg = 0.f;
    __syncthreads();

#pragma unroll 1
    for (int s = 0; s < WW - 1; ++s) {
        const int pp = s & 1;
        const float ys = xb[(size_t)tgt * WW + s];
        {
            const f4t* hc4 = (const f4t*)&s_hch2[pp][(tid & 3) * 16];
            float a = 0.f;
#pragma unroll
            for (int i = 0; i < 4; ++i) { f4t v = hc4[i]; DOT4(v, dlw_r, 4 * i, a); }
            a += __shfl_xor(a, 1, 64);
            a += __shfl_xor(a, 2, 64);
            float wo = (a + dlwb_r) * CLOG;
            float wn = __shfl_xor(wo, 4, 64);
            if (!(tid & 7)) { f2t st = {wo, wn}; *(f2t*)&s_wlvf[(tid >> 3) * 4] = st; }
        }
        __syncthreads();
        {
            const int w = tid >> 1, sw = w & 31;
            const h2t* udr = s_pool + w * 32;
            float a = 0.f;
#pragma unroll
            for (int j = 0; j < 16; ++j) {
                const int ep = (tid & 1) * 16 + j;
                f4t wl = s_wlv[ep];
                h2t u  = udr[ep ^ sw];
                float r0 = rcp_(ex2(wl.x + (float)u.x) + 1.f);
                float r1 = rcp_(ex2(wl.y + (float)u.y) + 1.f);
                a = fmaf(wl.z, r0, a);
                a = fmaf(wl.w, r1, a);
            }
            a += __shfl_xor(a, 1, 64);
            if (!(tid & 1)) s_soft[w] = ex2((dlvsum - 2.f * a) * L2E);
        }
        __syncthreads();
        float inv;
        {
            const int l = tid & 63;
            float sm = s_soft[l] + s_soft[64 + l];
            sm = wsum(sm);
            inv = rcp_(sm);
            const int e2 = tid & 31, pg = tid >> 5;
            float a0 = 0.f, a1 = 0.f;
#pragma unroll
            for (int j = 0; j < 16; ++j) {
                const int w = pg * 16 + j;
                float bw = s_soft[w];
                h2t hp = s_hseq2[w][e2 ^ (w & 31)];
                a0 = fmaf(bw, (float)hp.x, a0);
                a1 = fmaf(bw, (float)hp.y, a1);
            }
            a0 += __shfl_xor(a0, 32, 64);
            a1 += __shfl_xor(a1, 32, 64);
            if ((tid & 63) < 32) { f2t st = {a0, a1}; *(f2t*)&s_tmp[wq * 64 + e2 * 2] = st; }
        }
        __syncthreads();
        {
            const int l = tid & 63;
            float ctx = s_tmp[l] + s_tmp[64 + l] + s_tmp[128 + l] + s_tmp[192 + l];
            float term = ctx * inv * lp1_r;
            term = wsum(term);
            float yt = fmaf(ys, lp0, term + lpb);
            float gv = fmaf(yt, dwih_r, dbsum_r);
            const f4t* h4 = (const f4t*)&s_hch2[pp][0];
#pragma unroll
            for (int i = 0; i < 8; ++i) { f4t v = h4[i]; DOT4(v, dwhh_r, 4 * i, gv); }
            const int base = lane & ~3;
            float gi = __shfl(gv, base, 64);
            float gf = __shfl(gv, base + 1, 64);
            float g2 = __shfl(gv, base + 2, 64);
            float go = __shfl(gv, base + 3, 64);
            float c = sig_c(gf) * c_reg + sig_c(gi) * tanh_c(g2);
            float h = sig_c(go) * tanh_c(c);
            c_reg = c; h_reg = h;
            float hn = __shfl_xor(h, 4, 64);
            float cn = __shfl_xor(c, 4, 64);
            if (!(lane & 7)) {
                const int k = wq * 8 + (lane >> 3);
                s_hch2[pp ^ 1][k]      = pk2(h, hn);
                s_hch2[pp ^ 1][32 + k] = pk2(c, cn);
            }
        }
        __syncthreads();
    }
    {
        float term = 0.f;
        if (!(lane & 3)) term = h_reg * dly[uidx] + c_reg * dly[64 + uidx];
        term = wsum(term);
        if (lane == 0) s_tmp[wq] = term;
    }
    __syncthreads();
    if (tid == 0) out[b] = s_tmp[0] + s_tmp[1] + s_tmp[2] + s_tmp[3] + dlyb[0];
}

extern "C" void kernel_launch(void* const* d_in, const int* in_sizes, int n_in,
                              void* d_out, int out_size, void* d_ws, size_t ws_size,
                              hipStream_t stream) {
    (void)in_sizes; (void)n_in; (void)out_size;
    const float* x    = (const float*)d_in[0];
    const float* eWih = (const float*)d_in[1];
    const float* eWhh = (const float*)d_in[2];
    const float* ebih = (const float*)d_in[3];
    const float* ebhh = (const float*)d_in[4];
    const float* elv  = (const float*)d_in[5];
    const float* elw  = (const float*)d_in[6];
    const float* elwb = (const float*)d_in[7];
    const float* elu  = (const float*)d_in[8];
    const float* elub = (const float*)d_in[9];
    const float* dWih = (const float*)d_in[10];
    const float* dWhh = (const float*)d_in[11];
    const float* dbih = (const float*)d_in[12];
    const float* dbhh = (const float*)d_in[13];
    const float* dlv  = (const float*)d_in[14];
    const float* dlw  = (const float*)d_in[15];
    const float* dlwb = (const float*)d_in[16];
    const float* dlu  = (const float*)d_in[17];
    const float* dlub = (const float*)d_in[18];
    const float* dlp  = (const float*)d_in[19];
    const float* dlpb = (const float*)d_in[20];
    const float* dly  = (const float*)d_in[21];
    const float* dlyb = (const float*)d_in[22];
    const int*   tgt  = (const int*)d_in[23];
    float* out = (float*)d_out;

    const size_t need = (size_t)NB * WW * 32 * sizeof(h2t);  // 16 MiB
    if (d_ws && ws_size >= need) {
        darnn2_kernel<<<NB / 2, 256, 0, stream>>>(
            x, eWih, eWhh, ebih, ebhh, elv, elw, elwb, elu, elub,
            dWih, dWhh, dbih, dbhh, dlv, dlw, dlwb, dlu, dlub,
            dlp, dlpb, dly, dlyb, tgt, (h2t*)d_ws, out);
    } else {
        darnn1_kernel<<<NB, 256, 0, stream>>>(
            x, eWih, eWhh, ebih, ebhh, elv, elw, elwb, elu, elub,
            dWih, dWhh, dbih, dbhh, dlv, dlw, dlwb, dlu, dlub,
            dlp, dlpb, dly, dlyb, tgt, out);
    }
}